// Round 2
// 4667.375 us; speedup vs baseline: 1.1928x; 1.1928x over previous
//
#include <hip/hip_runtime.h>

typedef __attribute__((ext_vector_type(8))) short short8;
typedef __attribute__((ext_vector_type(4))) float f32x4;
typedef __attribute__((ext_vector_type(4))) int   i32x4;
typedef __attribute__((ext_vector_type(4))) float fvec4;
typedef __attribute__((ext_vector_type(4))) unsigned short u16x4;

#define B_ 64
#define T_ 256
#define H_ 512
#define NG 2048   // 4*H
#define BTH (64*256*512)
#define BH (64*512)

__device__ __forceinline__ float bf2f(unsigned short u) {
    return __builtin_bit_cast(float, ((unsigned)u) << 16);
}
__device__ __forceinline__ unsigned short f2bf(float f) {
    unsigned u = __builtin_bit_cast(unsigned, f);
    u += 0x7fffu + ((u >> 16) & 1u);   // RNE
    return (unsigned short)(u >> 16);
}
__device__ __forceinline__ float sigm(float x) { return 1.f / (1.f + __expf(-x)); }
__device__ __forceinline__ float tanh_f(float x) {
    x = fminf(15.f, fmaxf(-15.f, x));
    float e = __expf(-2.f * x);
    return (1.f - e) / (1.f + e);
}

// ---- coherent-point (L3) accesses via relaxed agent-scope atomics ----
__device__ __forceinline__ short8 load_frag_coh(const unsigned* p) {
    i32x4 w;
    w[0] = (int)__hip_atomic_load(p + 0, __ATOMIC_RELAXED, __HIP_MEMORY_SCOPE_AGENT);
    w[1] = (int)__hip_atomic_load(p + 1, __ATOMIC_RELAXED, __HIP_MEMORY_SCOPE_AGENT);
    w[2] = (int)__hip_atomic_load(p + 2, __ATOMIC_RELAXED, __HIP_MEMORY_SCOPE_AGENT);
    w[3] = (int)__hip_atomic_load(p + 3, __ATOMIC_RELAXED, __HIP_MEMORY_SCOPE_AGENT);
    return __builtin_bit_cast(short8, w);
}
__device__ __forceinline__ void store_coh(unsigned* p, unsigned v) {
    __hip_atomic_store(p, v, __ATOMIC_RELAXED, __HIP_MEMORY_SCOPE_AGENT);
}

// ---------------- prep: weight transpose f32[K,N] -> bf16[N,K] ----------------
__global__ void transpose_cvt(const float* __restrict__ Wi, const float* __restrict__ Wh,
                              unsigned short* __restrict__ Wt) {
    __shared__ float tile[64][65];
    int z = blockIdx.z;
    const float* src = (z < 2 ? Wi : Wh) + (size_t)(z & 1) * H_ * NG;
    unsigned short* dst = Wt + (size_t)z * NG * H_;
    int k0 = blockIdx.x * 64, n0 = blockIdx.y * 64;
    int tx = threadIdx.x & 63, ty = threadIdx.x >> 6;
#pragma unroll
    for (int p = 0; p < 16; ++p) {
        int r = (p << 2) + ty;
        tile[r][tx] = src[(size_t)(k0 + r) * NG + n0 + tx];
    }
    __syncthreads();
#pragma unroll
    for (int p = 0; p < 16; ++p) {
        int r = (p << 2) + ty;
        dst[(size_t)(n0 + r) * H_ + k0 + tx] = f2bf(tile[tx][r]);
    }
}

__global__ void cvt_bf16(const float* __restrict__ x, unsigned short* __restrict__ xb) {
    size_t i = ((size_t)blockIdx.x * 256 + threadIdx.x) * 4;
    fvec4 v = *(const fvec4*)&x[i];
    u16x4 o;
    o[0] = f2bf(v[0]); o[1] = f2bf(v[1]); o[2] = f2bf(v[2]); o[3] = f2bf(v[3]);
    *(u16x4*)&xb[i] = o;
}

// ---------------- big GEMM (layer-0 input gates only) ----------------
__global__ __launch_bounds__(256) void gemm_bt(
    const unsigned short* __restrict__ A, const unsigned short* __restrict__ Bt,
    const float* __restrict__ bias1, const float* __restrict__ bias2,
    unsigned short* __restrict__ C) {
    const int tid = threadIdx.x;
    const int wave = tid >> 6, lane = tid & 63;
    const int quad = lane >> 4, l15 = lane & 15;
    const int row0 = blockIdx.x * 64 + wave * 16;
    const int col0 = blockIdx.y * 64;
    f32x4 acc[4] = {};
    const unsigned short* ap = A + (size_t)(row0 + l15) * H_ + (quad << 3);
    const unsigned short* bp = Bt + (size_t)(col0 + l15) * H_ + (quad << 3);
#pragma unroll
    for (int kk = 0; kk < H_; kk += 32) {
        short8 a = *(const short8*)(ap + kk);
#pragma unroll
        for (int c4 = 0; c4 < 4; ++c4) {
            short8 b = *(const short8*)(bp + (size_t)(c4 << 4) * H_ + kk);
            acc[c4] = __builtin_amdgcn_mfma_f32_16x16x32_bf16(a, b, acc[c4], 0, 0, 0);
        }
    }
#pragma unroll
    for (int c4 = 0; c4 < 4; ++c4) {
        int col = col0 + (c4 << 4) + l15;
        float bs = bias1[col] + bias2[col];
#pragma unroll
        for (int r = 0; r < 4; ++r) {
            int row = row0 + (quad << 2) + r;
            int t = row & 255, b = row >> 8;
            C[((size_t)t * B_ + b) * NG + col] = f2bf(acc[c4][r] + bs);
        }
    }
}

// ---------------- grid barrier among one layer's 32 WGs ----------------
__device__ __forceinline__ void gbar_lite(unsigned* bar, unsigned target) {
    __syncthreads();
    if (threadIdx.x == 0) {
        __hip_atomic_fetch_add(bar, 1u, __ATOMIC_RELAXED, __HIP_MEMORY_SCOPE_AGENT);
        int spins = 0;
        while (__hip_atomic_load(bar, __ATOMIC_RELAXED, __HIP_MEMORY_SCOPE_AGENT) < target) {
            __builtin_amdgcn_s_sleep(1);
            if (++spins > 200000) break;   // failsafe: deadlock -> wrong answer, not hang
        }
    }
    __syncthreads();
}

// wait-only (no bump): all lanes spin on a monotone counter
__device__ __forceinline__ void wait_ge(const unsigned* bar, unsigned target) {
    int spins = 0;
    while (__hip_atomic_load(bar, __ATOMIC_RELAXED, __HIP_MEMORY_SCOPE_AGENT) < target) {
        __builtin_amdgcn_s_sleep(1);
        if (++spins > 400000) break;
    }
}

// ---------------- fused persistent 2-layer recurrent kernel ----------------
// 64 WGs x 256 thr. WGs 0..31: layer 0 (Wh0 slab in VGPRs, Gi precomputed,
// h0 history to L3, signals bar0). WGs 32..63: layer 1 (Wh1 slab in VGPRs,
// Wi1 slab in LDS, consumes h0 history after observing bar0, own all-to-all
// via bar1, ping-pong h1). Layer 0 never waits on layer 1 -> it runs ahead,
// layer 1 lags by ~1 step; wall time ~ (T+1) steps instead of 2T.
__global__ __launch_bounds__(256, 1) void lstm_fused(
    const unsigned short* __restrict__ Gi,   // [T][B][2048] bf16 (layer-0 gates incl. biases)
    const unsigned short* __restrict__ Wt,   // 4 slabs: Wi0^T, Wi1^T, Wh0^T, Wh1^T  [2048][512] bf16
    unsigned* __restrict__ h0h,              // [T+1][64][256] u32-packed bf16 h0 history
    unsigned* __restrict__ hb0, unsigned* __restrict__ hb1,  // layer-1 h ping-pong [64][256]
    const float* __restrict__ bi, const float* __restrict__ bh,
    float* __restrict__ out,                 // [B][T][512] f32 (layer-1 output)
    float* __restrict__ hT, float* __restrict__ cT,   // [L][B][512]
    unsigned* __restrict__ bar) {
    __shared__ unsigned short wi_lds[64 * 512];   // 64KB, fragment-linear layout
    const size_t NK = (size_t)NG * H_;
    const int tid = threadIdx.x;
    const int wave = tid >> 6, lane = tid & 63;
    const int quad = lane >> 4, l15 = lane & 15;
    const int m0 = wave << 4;
    unsigned* bar0 = bar;
    unsigned* bar1 = bar + 32;

    if (blockIdx.x < 32) {
        // ================= layer 0 =================
        const int j0 = (int)blockIdx.x << 4;
        const unsigned short* Wht = Wt + 2 * NK;
        short8 bw[64];
#pragma unroll
        for (int kb = 0; kb < 16; ++kb)
#pragma unroll
            for (int g = 0; g < 4; ++g)
                bw[kb * 4 + g] =
                    *(const short8*)&Wht[(size_t)((g << 9) + j0 + l15) * H_ + (kb << 5) + (quad << 3)];
#pragma unroll
        for (int i = 0; i < 64; ++i) asm volatile("" : "+v"(bw[i]));

        // zero h0 history slot 0 (own 16 cols, all 64 rows via 4 waves)
        if (!(l15 & 1)) {
#pragma unroll
            for (int r = 0; r < 4; ++r) {
                int b = m0 + (quad << 2) + r;
                store_coh(&h0h[(b << 8) + ((j0 + l15) >> 1)], 0u);
            }
        }
        float cc[4] = {0.f, 0.f, 0.f, 0.f};

        float gv[4][4];
#pragma unroll
        for (int r = 0; r < 4; ++r) {
            int b = m0 + (quad << 2) + r;
#pragma unroll
            for (int g = 0; g < 4; ++g)
                gv[g][r] = bf2f(Gi[(size_t)b * NG + (g << 9) + j0 + l15]);
        }
        gbar_lite(bar0, 32u);

        for (int t = 0; t < T_; ++t) {
            const unsigned* ap = h0h + ((size_t)t << 14) + ((m0 + l15) << 8) + (quad << 2);
            short8 ha[16];
#pragma unroll
            for (int kb = 0; kb < 16; ++kb) ha[kb] = load_frag_coh(ap + (kb << 4));

            f32x4 acc0 = {}, acc1 = {}, acc2 = {}, acc3 = {};
#pragma unroll
            for (int kb = 0; kb < 16; ++kb) {
                acc0 = __builtin_amdgcn_mfma_f32_16x16x32_bf16(ha[kb], bw[kb * 4 + 0], acc0, 0, 0, 0);
                acc1 = __builtin_amdgcn_mfma_f32_16x16x32_bf16(ha[kb], bw[kb * 4 + 1], acc1, 0, 0, 0);
                acc2 = __builtin_amdgcn_mfma_f32_16x16x32_bf16(ha[kb], bw[kb * 4 + 2], acc2, 0, 0, 0);
                acc3 = __builtin_amdgcn_mfma_f32_16x16x32_bf16(ha[kb], bw[kb * 4 + 3], acc3, 0, 0, 0);
            }

#pragma unroll
            for (int r = 0; r < 4; ++r) {
                int b = m0 + (quad << 2) + r;
                int jj = j0 + l15;
                float iv = sigm(acc0[r] + gv[0][r]);
                float fv = sigm(acc1[r] + gv[1][r]);
                float gg = tanh_f(acc2[r] + gv[2][r]);
                float ov = sigm(acc3[r] + gv[3][r]);
                float cn = fv * cc[r] + iv * gg;
                cc[r] = cn;
                float hv = ov * tanh_f(cn);
                unsigned short hb16 = f2bf(hv);
                unsigned packed = (unsigned)hb16 |
                                  (((unsigned)(unsigned short)__shfl_xor((int)hb16, 1)) << 16);
                if (!(l15 & 1))
                    store_coh(&h0h[((size_t)(t + 1) << 14) + (b << 8) + (jj >> 1)], packed);
                if (t == T_ - 1) {
                    hT[((size_t)b << 9) + jj] = hv;
                    cT[((size_t)b << 9) + jj] = cn;
                }
            }

            // prefetch Gi[t+1] BEFORE the barrier
            int tn = (t + 1) & (T_ - 1);
            float gn[4][4];
#pragma unroll
            for (int r = 0; r < 4; ++r) {
                int b = m0 + (quad << 2) + r;
#pragma unroll
                for (int g = 0; g < 4; ++g)
                    gn[g][r] = bf2f(Gi[((size_t)tn * B_ + b) * NG + (g << 9) + j0 + l15]);
            }
            gbar_lite(bar0, 32u * (t + 2));
#pragma unroll
            for (int r = 0; r < 4; ++r)
#pragma unroll
                for (int g = 0; g < 4; ++g) gv[g][r] = gn[g][r];
        }
    } else {
        // ================= layer 1 =================
        const int j0 = ((int)blockIdx.x - 32) << 4;
        const unsigned short* Wht = Wt + 3 * NK;
        short8 bw[64];
#pragma unroll
        for (int kb = 0; kb < 16; ++kb)
#pragma unroll
            for (int g = 0; g < 4; ++g)
                bw[kb * 4 + g] =
                    *(const short8*)&Wht[(size_t)((g << 9) + j0 + l15) * H_ + (kb << 5) + (quad << 3)];
#pragma unroll
        for (int i = 0; i < 64; ++i) asm volatile("" : "+v"(bw[i]));

        // stage Wi1 slab into LDS, fragment-linear:
        //   byte = kb*4096 + g*1024 + quad*256 + l15*16
        // -> each ds_read_b128 (fixed kb,g) reads a contiguous 1KB per wave: conflict-free
        const unsigned short* Wit = Wt + 1 * NK;
#pragma unroll
        for (int i2 = 0; i2 < 16; ++i2) {
            int c = i2 * 256 + tid;            // 4096 x 16B chunks
            int l = c & 15, q = (c >> 4) & 3, g = (c >> 6) & 3, kb = c >> 8;
            short8 v = *(const short8*)&Wit[(size_t)((g << 9) + j0 + l) * H_ + (kb << 5) + (q << 3)];
            *(short8*)((char*)wi_lds + ((size_t)c << 4)) = v;
        }
        const int wbase = (quad << 8) + (l15 << 4);   // per-thread fragment offset

        // layer-1 biases (not baked into any GEMM)
        float gb0 = bi[NG + j0 + l15]        + bh[NG + j0 + l15];
        float gb1 = bi[NG + 512 + j0 + l15]  + bh[NG + 512 + j0 + l15];
        float gb2 = bi[NG + 1024 + j0 + l15] + bh[NG + 1024 + j0 + l15];
        float gb3 = bi[NG + 1536 + j0 + l15] + bh[NG + 1536 + j0 + l15];

        // zero own h1(t=-1) slice
        if (!(l15 & 1)) {
#pragma unroll
            for (int r = 0; r < 4; ++r) {
                int b = m0 + (quad << 2) + r;
                store_coh(&hb0[(b << 8) + ((j0 + l15) >> 1)], 0u);
            }
        }
        float cc[4] = {0.f, 0.f, 0.f, 0.f};

        gbar_lite(bar1, 32u);   // covers LDS staging + h1 zero-init

        // prefetch h1(-1) fragments
        short8 ha[16];
        {
            const unsigned* ap1 = hb0 + ((m0 + l15) << 8) + (quad << 2);
#pragma unroll
            for (int kb = 0; kb < 16; ++kb) ha[kb] = load_frag_coh(ap1 + (kb << 4));
        }

        for (int t = 0; t < T_; ++t) {
            unsigned* hn = (t & 1) ? hb0 : hb1;

            // Wh1 part first (independent of layer 0)
            f32x4 acc0 = {}, acc1 = {}, acc2 = {}, acc3 = {};
#pragma unroll
            for (int kb = 0; kb < 16; ++kb) {
                acc0 = __builtin_amdgcn_mfma_f32_16x16x32_bf16(ha[kb], bw[kb * 4 + 0], acc0, 0, 0, 0);
                acc1 = __builtin_amdgcn_mfma_f32_16x16x32_bf16(ha[kb], bw[kb * 4 + 1], acc1, 0, 0, 0);
                acc2 = __builtin_amdgcn_mfma_f32_16x16x32_bf16(ha[kb], bw[kb * 4 + 2], acc2, 0, 0, 0);
                acc3 = __builtin_amdgcn_mfma_f32_16x16x32_bf16(ha[kb], bw[kb * 4 + 3], acc3, 0, 0, 0);
            }

            // wait until all 32 layer-0 WGs stored h0(t)  (after warm-up: already true)
            wait_ge(bar0, 32u * (t + 2));

            // Wi1 part: A = h0(t) from history, B from LDS
            const unsigned* ap0 = h0h + ((size_t)(t + 1) << 14) + ((m0 + l15) << 8) + (quad << 2);
#pragma unroll
            for (int kb = 0; kb < 16; ++kb) ha[kb] = load_frag_coh(ap0 + (kb << 4));
#pragma unroll
            for (int kb = 0; kb < 16; ++kb) {
                const char* base = (const char*)wi_lds + (kb << 12) + wbase;
                short8 w0 = *(const short8*)(base);
                short8 w1 = *(const short8*)(base + (1 << 10));
                short8 w2 = *(const short8*)(base + (2 << 10));
                short8 w3 = *(const short8*)(base + (3 << 10));
                acc0 = __builtin_amdgcn_mfma_f32_16x16x32_bf16(ha[kb], w0, acc0, 0, 0, 0);
                acc1 = __builtin_amdgcn_mfma_f32_16x16x32_bf16(ha[kb], w1, acc1, 0, 0, 0);
                acc2 = __builtin_amdgcn_mfma_f32_16x16x32_bf16(ha[kb], w2, acc2, 0, 0, 0);
                acc3 = __builtin_amdgcn_mfma_f32_16x16x32_bf16(ha[kb], w3, acc3, 0, 0, 0);
            }

#pragma unroll
            for (int r = 0; r < 4; ++r) {
                int b = m0 + (quad << 2) + r;
                int jj = j0 + l15;
                float iv = sigm(acc0[r] + gb0);
                float fv = sigm(acc1[r] + gb1);
                float gg = tanh_f(acc2[r] + gb2);
                float ov = sigm(acc3[r] + gb3);
                float cn = fv * cc[r] + iv * gg;
                cc[r] = cn;
                float hv = ov * tanh_f(cn);
                unsigned short hb16 = f2bf(hv);
                unsigned packed = (unsigned)hb16 |
                                  (((unsigned)(unsigned short)__shfl_xor((int)hb16, 1)) << 16);
                if (!(l15 & 1))
                    store_coh(&hn[(b << 8) + (jj >> 1)], packed);
                out[((size_t)((b << 8) + t)) * H_ + jj] = hv;
                if (t == T_ - 1) {
                    hT[BH + ((size_t)b << 9) + jj] = hv;
                    cT[BH + ((size_t)b << 9) + jj] = cn;
                }
            }

            gbar_lite(bar1, 32u * (t + 2));

            // prefetch h1(t) fragments for next step (buffer just made visible)
            const unsigned* apn = hn + ((m0 + l15) << 8) + (quad << 2);
#pragma unroll
            for (int kb = 0; kb < 16; ++kb) ha[kb] = load_frag_coh(apn + (kb << 4));
        }
    }
}

extern "C" void kernel_launch(void* const* d_in, const int* in_sizes, int n_in,
                              void* d_out, int out_size, void* d_ws, size_t ws_size,
                              hipStream_t stream) {
    const float* x  = (const float*)d_in[0];
    const float* Wi = (const float*)d_in[1];
    const float* Wh = (const float*)d_in[2];
    const float* bi = (const float*)d_in[3];
    const float* bh = (const float*)d_in[4];
    float* out = (float*)d_out;

    char* w = (char*)d_ws;
    const size_t NK = (size_t)NG * H_;
    unsigned short* Wt  = (unsigned short*)w;                  // 8 MB (4 slabs)
    unsigned short* xb  = Wt + 4 * NK;                         // 16 MB
    unsigned short* Gi  = xb + (size_t)16384 * H_;             // 64 MB (layer-0 gates)
    unsigned* h0h       = (unsigned*)(Gi + (size_t)16384 * NG);// (T+1)*64*256 u32 = 16.85 MB
    unsigned* hb0       = h0h + (size_t)(T_ + 1) * 16384;      // 64 KB
    unsigned* hb1       = hb0 + (BH / 2);                      // 64 KB
    unsigned* bar       = hb1 + (BH / 2);                      // counters

    hipMemsetAsync(bar, 0, 256, stream);

    transpose_cvt<<<dim3(8, 32, 4), 256, 0, stream>>>(Wi, Wh, Wt);
    cvt_bf16<<<8192, 256, 0, stream>>>(x, xb);

    // layer-0 input gates (bulk GEMM, biases baked in)
    gemm_bt<<<dim3(256, 32), 256, 0, stream>>>(xb, Wt + 0 * NK, bi, bh, Gi);

    // fused pipelined 2-layer recurrence
    lstm_fused<<<64, 256, 0, stream>>>(Gi, Wt, h0h, hb0, hb1, bi, bh,
                                       out, out + BTH, out + BTH + 2 * (size_t)BH, bar);
}

// Round 3
// 3823.534 us; speedup vs baseline: 1.4561x; 1.2207x over previous
//
#include <hip/hip_runtime.h>

typedef __attribute__((ext_vector_type(8))) short short8;
typedef __attribute__((ext_vector_type(4))) float f32x4;
typedef __attribute__((ext_vector_type(4))) int   i32x4;
typedef __attribute__((ext_vector_type(4))) float fvec4;
typedef __attribute__((ext_vector_type(4))) unsigned short u16x4;

#define B_ 64
#define T_ 256
#define H_ 512
#define NG 2048   // 4*H
#define BTH (64*256*512)
#define BH (64*512)

__device__ __forceinline__ float bf2f(unsigned short u) {
    return __builtin_bit_cast(float, ((unsigned)u) << 16);
}
__device__ __forceinline__ unsigned short f2bf(float f) {
    unsigned u = __builtin_bit_cast(unsigned, f);
    u += 0x7fffu + ((u >> 16) & 1u);   // RNE
    return (unsigned short)(u >> 16);
}
__device__ __forceinline__ float sigm(float x) { return 1.f / (1.f + __expf(-x)); }
__device__ __forceinline__ float tanh_f(float x) {
    x = fminf(15.f, fmaxf(-15.f, x));
    float e = __expf(-2.f * x);
    return (1.f - e) / (1.f + e);
}

// ---- coherent-point (L3) accesses via relaxed agent-scope atomics ----
__device__ __forceinline__ short8 load_frag_coh(const unsigned* p) {
    i32x4 w;
    w[0] = (int)__hip_atomic_load(p + 0, __ATOMIC_RELAXED, __HIP_MEMORY_SCOPE_AGENT);
    w[1] = (int)__hip_atomic_load(p + 1, __ATOMIC_RELAXED, __HIP_MEMORY_SCOPE_AGENT);
    w[2] = (int)__hip_atomic_load(p + 2, __ATOMIC_RELAXED, __HIP_MEMORY_SCOPE_AGENT);
    w[3] = (int)__hip_atomic_load(p + 3, __ATOMIC_RELAXED, __HIP_MEMORY_SCOPE_AGENT);
    return __builtin_bit_cast(short8, w);
}
__device__ __forceinline__ void store_coh(unsigned* p, unsigned v) {
    __hip_atomic_store(p, v, __ATOMIC_RELAXED, __HIP_MEMORY_SCOPE_AGENT);
}

// ---------------- prep: weight transpose f32[K,N] -> bf16[N,K] ----------------
__global__ void transpose_cvt(const float* __restrict__ Wi, const float* __restrict__ Wh,
                              unsigned short* __restrict__ Wt) {
    __shared__ float tile[64][65];
    int z = blockIdx.z;
    const float* src = (z < 2 ? Wi : Wh) + (size_t)(z & 1) * H_ * NG;
    unsigned short* dst = Wt + (size_t)z * NG * H_;
    int k0 = blockIdx.x * 64, n0 = blockIdx.y * 64;
    int tx = threadIdx.x & 63, ty = threadIdx.x >> 6;
#pragma unroll
    for (int p = 0; p < 16; ++p) {
        int r = (p << 2) + ty;
        tile[r][tx] = src[(size_t)(k0 + r) * NG + n0 + tx];
    }
    __syncthreads();
#pragma unroll
    for (int p = 0; p < 16; ++p) {
        int r = (p << 2) + ty;
        dst[(size_t)(n0 + r) * H_ + k0 + tx] = f2bf(tile[tx][r]);
    }
}

__global__ void cvt_bf16(const float* __restrict__ x, unsigned short* __restrict__ xb) {
    size_t i = ((size_t)blockIdx.x * 256 + threadIdx.x) * 4;
    fvec4 v = *(const fvec4*)&x[i];
    u16x4 o;
    o[0] = f2bf(v[0]); o[1] = f2bf(v[1]); o[2] = f2bf(v[2]); o[3] = f2bf(v[3]);
    *(u16x4*)&xb[i] = o;
}

// ---------------- big GEMM (layer-0 input gates only) ----------------
__global__ __launch_bounds__(256) void gemm_bt(
    const unsigned short* __restrict__ A, const unsigned short* __restrict__ Bt,
    const float* __restrict__ bias1, const float* __restrict__ bias2,
    unsigned short* __restrict__ C) {
    const int tid = threadIdx.x;
    const int wave = tid >> 6, lane = tid & 63;
    const int quad = lane >> 4, l15 = lane & 15;
    const int row0 = blockIdx.x * 64 + wave * 16;
    const int col0 = blockIdx.y * 64;
    f32x4 acc[4] = {};
    const unsigned short* ap = A + (size_t)(row0 + l15) * H_ + (quad << 3);
    const unsigned short* bp = Bt + (size_t)(col0 + l15) * H_ + (quad << 3);
#pragma unroll
    for (int kk = 0; kk < H_; kk += 32) {
        short8 a = *(const short8*)(ap + kk);
#pragma unroll
        for (int c4 = 0; c4 < 4; ++c4) {
            short8 b = *(const short8*)(bp + (size_t)(c4 << 4) * H_ + kk);
            acc[c4] = __builtin_amdgcn_mfma_f32_16x16x32_bf16(a, b, acc[c4], 0, 0, 0);
        }
    }
#pragma unroll
    for (int c4 = 0; c4 < 4; ++c4) {
        int col = col0 + (c4 << 4) + l15;
        float bs = bias1[col] + bias2[col];
#pragma unroll
        for (int r = 0; r < 4; ++r) {
            int row = row0 + (quad << 2) + r;
            int t = row & 255, b = row >> 8;
            C[((size_t)t * B_ + b) * NG + col] = f2bf(acc[c4][r] + bs);
        }
    }
}

// ---------------- distributed-flag barrier (no central RMW) ----------------
// Producer: own-slot store (after __syncthreads drained sc1 data stores).
// Consumer: all lanes poll the 32-word flag line (coalesced) until min >= target.
__device__ __forceinline__ void flag_wait(const unsigned* flags, unsigned target) {
    int spins = 0;
    for (;;) {
        unsigned v = __hip_atomic_load(flags + (threadIdx.x & 31), __ATOMIC_RELAXED,
                                       __HIP_MEMORY_SCOPE_AGENT);
        if (__all((int)(v >= target))) break;
        __builtin_amdgcn_s_sleep(1);
        if (++spins > 400000) break;   // failsafe: wrong answer, not hang
    }
    asm volatile("" ::: "memory");     // no compile-time hoisting of data loads above poll
}
__device__ __forceinline__ void flag_bar(unsigned* flags, int myslot, unsigned target) {
    __syncthreads();   // all waves' prior sc1 data stores drained (vmcnt 0) before flag store
    if (threadIdx.x == 0) store_coh(flags + myslot, target);
    flag_wait(flags, target);
}

// ---------------- fused persistent 2-layer recurrent kernel ----------------
// 64 WGs x 256 thr. WGs 0..31: layer 0; WGs 32..63: layer 1 (lags ~1 step).
// h0 goes through a write-once history buffer (plain vectorized loads are
// coherence-safe: fresh addresses each step, L2 invalidated at dispatch).
// h1 ping-pong buffers reuse addresses -> keep L2-bypassing atomic loads.
__global__ __launch_bounds__(256, 1) void lstm_fused(
    const unsigned short* __restrict__ Gi,   // [T][B][2048] bf16 (layer-0 gates incl. biases)
    const unsigned short* __restrict__ Wt,   // 4 slabs: Wi0^T, Wi1^T, Wh0^T, Wh1^T  [2048][512] bf16
    unsigned* __restrict__ h0h,              // [T+1][64][256] u32-packed bf16 h0 history
    unsigned* __restrict__ hb0, unsigned* __restrict__ hb1,  // layer-1 h ping-pong [64][256]
    const float* __restrict__ bi, const float* __restrict__ bh,
    float* __restrict__ out,                 // [B][T][512] f32 (layer-1 output)
    float* __restrict__ hT, float* __restrict__ cT,   // [L][B][512]
    unsigned* __restrict__ flags) {          // [0..31]=layer0, [32..63]=layer1
    __shared__ unsigned short wi_lds[64 * 512];   // 64KB, fragment-linear layout
    const size_t NK = (size_t)NG * H_;
    const int tid = threadIdx.x;
    const int wave = tid >> 6, lane = tid & 63;
    const int quad = lane >> 4, l15 = lane & 15;
    const int m0 = wave << 4;
    unsigned* flag0 = flags;
    unsigned* flag1 = flags + 32;

    if (blockIdx.x < 32) {
        // ================= layer 0 =================
        const int slot = (int)blockIdx.x;
        const int j0 = slot << 4;
        const unsigned short* Wht = Wt + 2 * NK;
        short8 bw[64];
#pragma unroll
        for (int kb = 0; kb < 16; ++kb)
#pragma unroll
            for (int g = 0; g < 4; ++g)
                bw[kb * 4 + g] =
                    *(const short8*)&Wht[(size_t)((g << 9) + j0 + l15) * H_ + (kb << 5) + (quad << 3)];
#pragma unroll
        for (int i = 0; i < 64; ++i) asm volatile("" : "+v"(bw[i]));

        // zero h0 history slot 0 (own 16 cols, all 64 rows via 4 waves)
        if (!(l15 & 1)) {
#pragma unroll
            for (int r = 0; r < 4; ++r) {
                int b = m0 + (quad << 2) + r;
                store_coh(&h0h[(b << 8) + ((j0 + l15) >> 1)], 0u);
            }
        }
        float cc[4] = {0.f, 0.f, 0.f, 0.f};
        flag_bar(flag0, slot, 1u);

        for (int t = 0; t < T_; ++t) {
            // h(t-1) fragments: plain vectorized loads from write-once history
            const unsigned* ap = h0h + ((size_t)t << 14) + ((m0 + l15) << 8) + (quad << 2);
            short8 ha[16];
#pragma unroll
            for (int kb = 0; kb < 16; ++kb) ha[kb] = *(const short8*)(ap + (kb << 4));

            // Gi[t] loads issued alongside (consumed at elementwise)
            float gv[4][4];
#pragma unroll
            for (int r = 0; r < 4; ++r) {
                int b = m0 + (quad << 2) + r;
#pragma unroll
                for (int g = 0; g < 4; ++g)
                    gv[g][r] = bf2f(Gi[((size_t)t * B_ + b) * NG + (g << 9) + j0 + l15]);
            }

            f32x4 acc0 = {}, acc1 = {}, acc2 = {}, acc3 = {};
#pragma unroll
            for (int kb = 0; kb < 16; ++kb) {
                acc0 = __builtin_amdgcn_mfma_f32_16x16x32_bf16(ha[kb], bw[kb * 4 + 0], acc0, 0, 0, 0);
                acc1 = __builtin_amdgcn_mfma_f32_16x16x32_bf16(ha[kb], bw[kb * 4 + 1], acc1, 0, 0, 0);
                acc2 = __builtin_amdgcn_mfma_f32_16x16x32_bf16(ha[kb], bw[kb * 4 + 2], acc2, 0, 0, 0);
                acc3 = __builtin_amdgcn_mfma_f32_16x16x32_bf16(ha[kb], bw[kb * 4 + 3], acc3, 0, 0, 0);
            }

#pragma unroll
            for (int r = 0; r < 4; ++r) {
                int b = m0 + (quad << 2) + r;
                int jj = j0 + l15;
                float iv = sigm(acc0[r] + gv[0][r]);
                float fv = sigm(acc1[r] + gv[1][r]);
                float gg = tanh_f(acc2[r] + gv[2][r]);
                float ov = sigm(acc3[r] + gv[3][r]);
                float cn = fv * cc[r] + iv * gg;
                cc[r] = cn;
                float hv = ov * tanh_f(cn);
                unsigned short hb16 = f2bf(hv);
                unsigned packed = (unsigned)hb16 |
                                  (((unsigned)(unsigned short)__shfl_xor((int)hb16, 1)) << 16);
                if (!(l15 & 1))
                    store_coh(&h0h[((size_t)(t + 1) << 14) + (b << 8) + (jj >> 1)], packed);
                if (t == T_ - 1) {
                    hT[((size_t)b << 9) + jj] = hv;
                    cT[((size_t)b << 9) + jj] = cn;
                }
            }

            flag_bar(flag0, slot, 32u ? (unsigned)(t + 2) : 0u);
        }
    } else {
        // ================= layer 1 =================
        const int slot = (int)blockIdx.x - 32;
        const int j0 = slot << 4;
        const unsigned short* Wht = Wt + 3 * NK;
        short8 bw[64];
#pragma unroll
        for (int kb = 0; kb < 16; ++kb)
#pragma unroll
            for (int g = 0; g < 4; ++g)
                bw[kb * 4 + g] =
                    *(const short8*)&Wht[(size_t)((g << 9) + j0 + l15) * H_ + (kb << 5) + (quad << 3)];
#pragma unroll
        for (int i = 0; i < 64; ++i) asm volatile("" : "+v"(bw[i]));

        // stage Wi1 slab into LDS, fragment-linear:
        //   byte = kb*4096 + g*1024 + quad*256 + l15*16
        const unsigned short* Wit = Wt + 1 * NK;
#pragma unroll
        for (int i2 = 0; i2 < 16; ++i2) {
            int c = i2 * 256 + tid;            // 4096 x 16B chunks
            int l = c & 15, q = (c >> 4) & 3, g = (c >> 6) & 3, kb = c >> 8;
            short8 v = *(const short8*)&Wit[(size_t)((g << 9) + j0 + l) * H_ + (kb << 5) + (q << 3)];
            *(short8*)((char*)wi_lds + ((size_t)c << 4)) = v;
        }
        const int wbase = (quad << 8) + (l15 << 4);

        float gb0 = bi[NG + j0 + l15]        + bh[NG + j0 + l15];
        float gb1 = bi[NG + 512 + j0 + l15]  + bh[NG + 512 + j0 + l15];
        float gb2 = bi[NG + 1024 + j0 + l15] + bh[NG + 1024 + j0 + l15];
        float gb3 = bi[NG + 1536 + j0 + l15] + bh[NG + 1536 + j0 + l15];

        if (!(l15 & 1)) {
#pragma unroll
            for (int r = 0; r < 4; ++r) {
                int b = m0 + (quad << 2) + r;
                store_coh(&hb0[(b << 8) + ((j0 + l15) >> 1)], 0u);
            }
        }
        float cc[4] = {0.f, 0.f, 0.f, 0.f};
        flag_bar(flag1, slot, 1u);   // covers LDS staging + h1 zero-init

        // prefetch h1(-1) (atomic: ping-pong addresses) and h0(0) (plain: history)
        short8 ha1[16], ha0[16];
        {
            const unsigned* ap1 = hb0 + ((m0 + l15) << 8) + (quad << 2);
#pragma unroll
            for (int kb = 0; kb < 16; ++kb) ha1[kb] = load_frag_coh(ap1 + (kb << 4));
        }
        flag_wait(flag0, 2u);        // h0(0) visible
        {
            const unsigned* ap0 = h0h + ((size_t)1 << 14) + ((m0 + l15) << 8) + (quad << 2);
#pragma unroll
            for (int kb = 0; kb < 16; ++kb) ha0[kb] = *(const short8*)(ap0 + (kb << 4));
        }

        for (int t = 0; t < T_; ++t) {
            unsigned* hn = (t & 1) ? hb0 : hb1;

            f32x4 acc0 = {}, acc1 = {}, acc2 = {}, acc3 = {};
            // Wh1 x h1(t-1)
#pragma unroll
            for (int kb = 0; kb < 16; ++kb) {
                acc0 = __builtin_amdgcn_mfma_f32_16x16x32_bf16(ha1[kb], bw[kb * 4 + 0], acc0, 0, 0, 0);
                acc1 = __builtin_amdgcn_mfma_f32_16x16x32_bf16(ha1[kb], bw[kb * 4 + 1], acc1, 0, 0, 0);
                acc2 = __builtin_amdgcn_mfma_f32_16x16x32_bf16(ha1[kb], bw[kb * 4 + 2], acc2, 0, 0, 0);
                acc3 = __builtin_amdgcn_mfma_f32_16x16x32_bf16(ha1[kb], bw[kb * 4 + 3], acc3, 0, 0, 0);
            }
            // Wi1 x h0(t) (B-fragments from LDS)
#pragma unroll
            for (int kb = 0; kb < 16; ++kb) {
                const char* base = (const char*)wi_lds + (kb << 12) + wbase;
                short8 w0 = *(const short8*)(base);
                short8 w1 = *(const short8*)(base + (1 << 10));
                short8 w2 = *(const short8*)(base + (2 << 10));
                short8 w3 = *(const short8*)(base + (3 << 10));
                acc0 = __builtin_amdgcn_mfma_f32_16x16x32_bf16(ha0[kb], w0, acc0, 0, 0, 0);
                acc1 = __builtin_amdgcn_mfma_f32_16x16x32_bf16(ha0[kb], w1, acc1, 0, 0, 0);
                acc2 = __builtin_amdgcn_mfma_f32_16x16x32_bf16(ha0[kb], w2, acc2, 0, 0, 0);
                acc3 = __builtin_amdgcn_mfma_f32_16x16x32_bf16(ha0[kb], w3, acc3, 0, 0, 0);
            }

#pragma unroll
            for (int r = 0; r < 4; ++r) {
                int b = m0 + (quad << 2) + r;
                int jj = j0 + l15;
                float iv = sigm(acc0[r] + gb0);
                float fv = sigm(acc1[r] + gb1);
                float gg = tanh_f(acc2[r] + gb2);
                float ov = sigm(acc3[r] + gb3);
                float cn = fv * cc[r] + iv * gg;
                cc[r] = cn;
                float hv = ov * tanh_f(cn);
                unsigned short hb16 = f2bf(hv);
                unsigned packed = (unsigned)hb16 |
                                  (((unsigned)(unsigned short)__shfl_xor((int)hb16, 1)) << 16);
                if (!(l15 & 1))
                    store_coh(&hn[(b << 8) + (jj >> 1)], packed);
                out[((size_t)((b << 8) + t)) * H_ + jj] = hv;
                if (t == T_ - 1) {
                    hT[BH + ((size_t)b << 9) + jj] = hv;
                    cT[BH + ((size_t)b << 9) + jj] = cn;
                }
            }

            flag_bar(flag1, slot, (unsigned)(t + 2));

            if (t < T_ - 1) {
                // h0(t+1): wait layer-0 (instant once it runs ahead) then plain loads
                flag_wait(flag0, (unsigned)(t + 3));
                const unsigned* ap0 =
                    h0h + ((size_t)(t + 2) << 14) + ((m0 + l15) << 8) + (quad << 2);
#pragma unroll
                for (int kb = 0; kb < 16; ++kb) ha0[kb] = *(const short8*)(ap0 + (kb << 4));
                // h1(t): atomic loads from the buffer just published
                const unsigned* apn = hn + ((m0 + l15) << 8) + (quad << 2);
#pragma unroll
                for (int kb = 0; kb < 16; ++kb) ha1[kb] = load_frag_coh(apn + (kb << 4));
            }
        }
    }
}

extern "C" void kernel_launch(void* const* d_in, const int* in_sizes, int n_in,
                              void* d_out, int out_size, void* d_ws, size_t ws_size,
                              hipStream_t stream) {
    const float* x  = (const float*)d_in[0];
    const float* Wi = (const float*)d_in[1];
    const float* Wh = (const float*)d_in[2];
    const float* bi = (const float*)d_in[3];
    const float* bh = (const float*)d_in[4];
    float* out = (float*)d_out;

    char* w = (char*)d_ws;
    const size_t NK = (size_t)NG * H_;
    unsigned short* Wt  = (unsigned short*)w;                  // 8 MB (4 slabs)
    unsigned short* xb  = Wt + 4 * NK;                         // 16 MB
    unsigned short* Gi  = xb + (size_t)16384 * H_;             // 64 MB (layer-0 gates)
    unsigned* h0h       = (unsigned*)(Gi + (size_t)16384 * NG);// (T+1)*64*256 u32 = 16.85 MB
    unsigned* hb0       = h0h + (size_t)(T_ + 1) * 16384;      // 64 KB
    unsigned* hb1       = hb0 + (BH / 2);                      // 64 KB
    unsigned* flags     = hb1 + (BH / 2);                      // 64 words

    hipMemsetAsync(flags, 0, 256, stream);

    transpose_cvt<<<dim3(8, 32, 4), 256, 0, stream>>>(Wi, Wh, Wt);
    cvt_bf16<<<8192, 256, 0, stream>>>(x, xb);

    // layer-0 input gates (bulk GEMM, biases baked in)
    gemm_bt<<<dim3(256, 32), 256, 0, stream>>>(xb, Wt + 0 * NK, bi, bh, Gi);

    // fused pipelined 2-layer recurrence
    lstm_fused<<<64, 256, 0, stream>>>(Gi, Wt, h0h, hb0, hb1, bi, bh,
                                       out, out + BTH, out + BTH + 2 * (size_t)BH, flags);
}

// Round 4
// 2497.148 us; speedup vs baseline: 2.2295x; 1.5312x over previous
//
#include <hip/hip_runtime.h>

typedef __attribute__((ext_vector_type(8))) short short8;
typedef __attribute__((ext_vector_type(4))) float f32x4;
typedef __attribute__((ext_vector_type(4))) int   i32x4;
typedef __attribute__((ext_vector_type(4))) float fvec4;
typedef __attribute__((ext_vector_type(4))) unsigned short u16x4;

#define B_ 64
#define T_ 256
#define H_ 512
#define NG 2048   // 4*H
#define BTH (64*256*512)
#define BH (64*512)

__device__ __forceinline__ float bf2f(unsigned short u) {
    return __builtin_bit_cast(float, ((unsigned)u) << 16);
}
__device__ __forceinline__ unsigned short f2bf(float f) {
    unsigned u = __builtin_bit_cast(unsigned, f);
    u += 0x7fffu + ((u >> 16) & 1u);   // RNE
    return (unsigned short)(u >> 16);
}
__device__ __forceinline__ float sigm(float x) { return 1.f / (1.f + __expf(-x)); }
__device__ __forceinline__ float tanh_f(float x) {
    x = fminf(15.f, fmaxf(-15.f, x));
    float e = __expf(-2.f * x);
    return (1.f - e) / (1.f + e);
}

__device__ __forceinline__ void store_coh(unsigned* p, unsigned v) {
    __hip_atomic_store(p, v, __ATOMIC_RELAXED, __HIP_MEMORY_SCOPE_AGENT);
}

// ---------------- prep: weight transpose f32[K,N] -> bf16[N,K] ----------------
__global__ void transpose_cvt(const float* __restrict__ Wi, const float* __restrict__ Wh,
                              unsigned short* __restrict__ Wt) {
    __shared__ float tile[64][65];
    int z = blockIdx.z;
    const float* src = (z < 2 ? Wi : Wh) + (size_t)(z & 1) * H_ * NG;
    unsigned short* dst = Wt + (size_t)z * NG * H_;
    int k0 = blockIdx.x * 64, n0 = blockIdx.y * 64;
    int tx = threadIdx.x & 63, ty = threadIdx.x >> 6;
#pragma unroll
    for (int p = 0; p < 16; ++p) {
        int r = (p << 2) + ty;
        tile[r][tx] = src[(size_t)(k0 + r) * NG + n0 + tx];
    }
    __syncthreads();
#pragma unroll
    for (int p = 0; p < 16; ++p) {
        int r = (p << 2) + ty;
        dst[(size_t)(n0 + r) * H_ + k0 + tx] = f2bf(tile[tx][r]);
    }
}

__global__ void cvt_bf16(const float* __restrict__ x, unsigned short* __restrict__ xb) {
    size_t i = ((size_t)blockIdx.x * 256 + threadIdx.x) * 4;
    fvec4 v = *(const fvec4*)&x[i];
    u16x4 o;
    o[0] = f2bf(v[0]); o[1] = f2bf(v[1]); o[2] = f2bf(v[2]); o[3] = f2bf(v[3]);
    *(u16x4*)&xb[i] = o;
}

// ---------------- big GEMM (layer-0 input gates only) ----------------
__global__ __launch_bounds__(256) void gemm_bt(
    const unsigned short* __restrict__ A, const unsigned short* __restrict__ Bt,
    const float* __restrict__ bias1, const float* __restrict__ bias2,
    unsigned short* __restrict__ C) {
    const int tid = threadIdx.x;
    const int wave = tid >> 6, lane = tid & 63;
    const int quad = lane >> 4, l15 = lane & 15;
    const int row0 = blockIdx.x * 64 + wave * 16;
    const int col0 = blockIdx.y * 64;
    f32x4 acc[4] = {};
    const unsigned short* ap = A + (size_t)(row0 + l15) * H_ + (quad << 3);
    const unsigned short* bp = Bt + (size_t)(col0 + l15) * H_ + (quad << 3);
#pragma unroll
    for (int kk = 0; kk < H_; kk += 32) {
        short8 a = *(const short8*)(ap + kk);
#pragma unroll
        for (int c4 = 0; c4 < 4; ++c4) {
            short8 b = *(const short8*)(bp + (size_t)(c4 << 4) * H_ + kk);
            acc[c4] = __builtin_amdgcn_mfma_f32_16x16x32_bf16(a, b, acc[c4], 0, 0, 0);
        }
    }
#pragma unroll
    for (int c4 = 0; c4 < 4; ++c4) {
        int col = col0 + (c4 << 4) + l15;
        float bs = bias1[col] + bias2[col];
#pragma unroll
        for (int r = 0; r < 4; ++r) {
            int row = row0 + (quad << 2) + r;
            int t = row & 255, b = row >> 8;
            C[((size_t)t * B_ + b) * NG + col] = f2bf(acc[c4][r] + bs);
        }
    }
}

// ---------------- distributed-flag barrier, split into publish / wait ----------
// publish: __syncthreads drains all waves' sc1 data stores (vmcnt 0) BEFORE the
// flag store. Independent memory ops (prefetches, out-stores) go between publish
// and wait so their latency overlaps the poll.
__device__ __forceinline__ void flag_publish(unsigned* flags, int myslot, unsigned target) {
    __syncthreads();
    if (threadIdx.x == 0) store_coh(flags + myslot, target);
}
__device__ __forceinline__ void flag_wait(const unsigned* flags, unsigned target) {
    int spins = 0;
    for (;;) {
        unsigned v = __hip_atomic_load(flags + (threadIdx.x & 31), __ATOMIC_RELAXED,
                                       __HIP_MEMORY_SCOPE_AGENT);
        if (__all((int)(v >= target))) break;
        __builtin_amdgcn_s_sleep(1);
        if (++spins > 400000) break;   // failsafe: wrong answer, not hang
    }
    asm volatile("" ::: "memory");     // no compile-time hoisting of data loads above poll
}

// ---------------- fused persistent 2-layer recurrent kernel ----------------
// 64 WGs x 256 thr. WGs 0..31: layer 0; WGs 32..63: layer 1 (lags ~1 step).
// BOTH h0 and h1 go through write-once history buffers (plain vectorized loads
// are coherence-safe: fresh addresses each step, caches invalidated at dispatch
// boundaries). Producers store with sc1 (write-through to coherent point);
// visibility ordered by syncthreads-drain -> flag store -> poll.
__global__ __launch_bounds__(256, 1) void lstm_fused(
    const unsigned short* __restrict__ Gi,   // [T][B][2048] bf16 (layer-0 gates incl. biases)
    const unsigned short* __restrict__ Wt,   // 4 slabs: Wi0^T, Wi1^T, Wh0^T, Wh1^T  [2048][512] bf16
    unsigned* __restrict__ h0h,              // [T+1][64][256] u32-packed bf16 h0 history
    unsigned* __restrict__ h1h,              // [T+1][64][256] u32-packed bf16 h1 history
    const float* __restrict__ bi, const float* __restrict__ bh,
    float* __restrict__ out,                 // [B][T][512] f32 (layer-1 output)
    float* __restrict__ hT, float* __restrict__ cT,   // [L][B][512]
    unsigned* __restrict__ flags) {          // [0..31]=layer0, [32..63]=layer1
    __shared__ unsigned short wi_lds[64 * 512];   // 64KB, fragment-linear layout
    const size_t NK = (size_t)NG * H_;
    const int tid = threadIdx.x;
    const int wave = tid >> 6, lane = tid & 63;
    const int quad = lane >> 4, l15 = lane & 15;
    const int m0 = wave << 4;
    unsigned* flag0 = flags;
    unsigned* flag1 = flags + 32;

    if (blockIdx.x < 32) {
        // ================= layer 0 =================
        const int slot = (int)blockIdx.x;
        const int j0 = slot << 4;
        const unsigned short* Wht = Wt + 2 * NK;
        short8 bw[64];
#pragma unroll
        for (int kb = 0; kb < 16; ++kb)
#pragma unroll
            for (int g = 0; g < 4; ++g)
                bw[kb * 4 + g] =
                    *(const short8*)&Wht[(size_t)((g << 9) + j0 + l15) * H_ + (kb << 5) + (quad << 3)];
#pragma unroll
        for (int i = 0; i < 64; ++i) asm volatile("" : "+v"(bw[i]));

        // zero h0 history slot 0 (own 16 cols, all 64 rows via 4 waves)
        if (!(l15 & 1)) {
#pragma unroll
            for (int r = 0; r < 4; ++r) {
                int b = m0 + (quad << 2) + r;
                store_coh(&h0h[(b << 8) + ((j0 + l15) >> 1)], 0u);
            }
        }
        float cc[4] = {0.f, 0.f, 0.f, 0.f};

        flag_publish(flag0, slot, 1u);
        // Gi[0] prefetch in the publish/wait gap
        float gv[4][4];
#pragma unroll
        for (int r = 0; r < 4; ++r) {
            int b = m0 + (quad << 2) + r;
#pragma unroll
            for (int g = 0; g < 4; ++g)
                gv[g][r] = bf2f(Gi[(size_t)b * NG + (g << 9) + j0 + l15]);
        }
        flag_wait(flag0, 1u);

        for (int t = 0; t < T_; ++t) {
            // h(t-1) fragments: plain vectorized loads from write-once history
            const unsigned* ap = h0h + ((size_t)t << 14) + ((m0 + l15) << 8) + (quad << 2);
            short8 ha[16];
#pragma unroll
            for (int kb = 0; kb < 16; ++kb) ha[kb] = *(const short8*)(ap + (kb << 4));

            f32x4 acc0 = {}, acc1 = {}, acc2 = {}, acc3 = {};
#pragma unroll
            for (int kb = 0; kb < 16; ++kb) {
                acc0 = __builtin_amdgcn_mfma_f32_16x16x32_bf16(ha[kb], bw[kb * 4 + 0], acc0, 0, 0, 0);
                acc1 = __builtin_amdgcn_mfma_f32_16x16x32_bf16(ha[kb], bw[kb * 4 + 1], acc1, 0, 0, 0);
                acc2 = __builtin_amdgcn_mfma_f32_16x16x32_bf16(ha[kb], bw[kb * 4 + 2], acc2, 0, 0, 0);
                acc3 = __builtin_amdgcn_mfma_f32_16x16x32_bf16(ha[kb], bw[kb * 4 + 3], acc3, 0, 0, 0);
            }

            float hvv[4];
#pragma unroll
            for (int r = 0; r < 4; ++r) {
                int b = m0 + (quad << 2) + r;
                int jj = j0 + l15;
                float iv = sigm(acc0[r] + gv[0][r]);
                float fv = sigm(acc1[r] + gv[1][r]);
                float gg = tanh_f(acc2[r] + gv[2][r]);
                float ov = sigm(acc3[r] + gv[3][r]);
                float cn = fv * cc[r] + iv * gg;
                cc[r] = cn;
                float hv = ov * tanh_f(cn);
                hvv[r] = hv;
                unsigned short hb16 = f2bf(hv);
                unsigned packed = (unsigned)hb16 |
                                  (((unsigned)(unsigned short)__shfl_xor((int)hb16, 1)) << 16);
                if (!(l15 & 1))
                    store_coh(&h0h[((size_t)(t + 1) << 14) + (b << 8) + (jj >> 1)], packed);
            }

            // publish h0(t); prefetch Gi[t+1] while peers converge
            flag_publish(flag0, slot, (unsigned)(t + 2));
            int tn = (t + 1) & (T_ - 1);
            float gn[4][4];
#pragma unroll
            for (int r = 0; r < 4; ++r) {
                int b = m0 + (quad << 2) + r;
#pragma unroll
                for (int g = 0; g < 4; ++g)
                    gn[g][r] = bf2f(Gi[((size_t)tn * B_ + b) * NG + (g << 9) + j0 + l15]);
            }
            if (t == T_ - 1) {
#pragma unroll
                for (int r = 0; r < 4; ++r) {
                    int b = m0 + (quad << 2) + r;
                    int jj = j0 + l15;
                    hT[((size_t)b << 9) + jj] = hvv[r];
                    cT[((size_t)b << 9) + jj] = cc[r];
                }
            }
            flag_wait(flag0, (unsigned)(t + 2));
#pragma unroll
            for (int r = 0; r < 4; ++r)
#pragma unroll
                for (int g = 0; g < 4; ++g) gv[g][r] = gn[g][r];
        }
    } else {
        // ================= layer 1 =================
        const int slot = (int)blockIdx.x - 32;
        const int j0 = slot << 4;
        const unsigned short* Wht = Wt + 3 * NK;
        short8 bw[64];
#pragma unroll
        for (int kb = 0; kb < 16; ++kb)
#pragma unroll
            for (int g = 0; g < 4; ++g)
                bw[kb * 4 + g] =
                    *(const short8*)&Wht[(size_t)((g << 9) + j0 + l15) * H_ + (kb << 5) + (quad << 3)];
#pragma unroll
        for (int i = 0; i < 64; ++i) asm volatile("" : "+v"(bw[i]));

        // stage Wi1 slab into LDS, fragment-linear:
        //   byte = kb*4096 + g*1024 + quad*256 + l15*16
        const unsigned short* Wit = Wt + 1 * NK;
#pragma unroll
        for (int i2 = 0; i2 < 16; ++i2) {
            int c = i2 * 256 + tid;            // 4096 x 16B chunks
            int l = c & 15, q = (c >> 4) & 3, g = (c >> 6) & 3, kb = c >> 8;
            short8 v = *(const short8*)&Wit[(size_t)((g << 9) + j0 + l) * H_ + (kb << 5) + (q << 3)];
            *(short8*)((char*)wi_lds + ((size_t)c << 4)) = v;
        }
        const int wbase = (quad << 8) + (l15 << 4);

        float gb0 = bi[NG + j0 + l15]        + bh[NG + j0 + l15];
        float gb1 = bi[NG + 512 + j0 + l15]  + bh[NG + 512 + j0 + l15];
        float gb2 = bi[NG + 1024 + j0 + l15] + bh[NG + 1024 + j0 + l15];
        float gb3 = bi[NG + 1536 + j0 + l15] + bh[NG + 1536 + j0 + l15];

        // zero own h1 history slot 0
        if (!(l15 & 1)) {
#pragma unroll
            for (int r = 0; r < 4; ++r) {
                int b = m0 + (quad << 2) + r;
                store_coh(&h1h[(b << 8) + ((j0 + l15) >> 1)], 0u);
            }
        }
        float cc[4] = {0.f, 0.f, 0.f, 0.f};
        flag_publish(flag1, slot, 1u);   // covers LDS staging + h1 zero-init
        flag_wait(flag1, 1u);

        // prefetch h1(-1) from slot 0 and h0(0) from slot 1 (both plain b128)
        short8 ha1[16], ha0[16];
        {
            const unsigned* ap1 = h1h + ((m0 + l15) << 8) + (quad << 2);
#pragma unroll
            for (int kb = 0; kb < 16; ++kb) ha1[kb] = *(const short8*)(ap1 + (kb << 4));
        }
        flag_wait(flag0, 2u);        // h0(0) visible
        {
            const unsigned* ap0 = h0h + ((size_t)1 << 14) + ((m0 + l15) << 8) + (quad << 2);
#pragma unroll
            for (int kb = 0; kb < 16; ++kb) ha0[kb] = *(const short8*)(ap0 + (kb << 4));
        }

        for (int t = 0; t < T_; ++t) {
            f32x4 acc0 = {}, acc1 = {}, acc2 = {}, acc3 = {};
            // Wh1 x h1(t-1)
#pragma unroll
            for (int kb = 0; kb < 16; ++kb) {
                acc0 = __builtin_amdgcn_mfma_f32_16x16x32_bf16(ha1[kb], bw[kb * 4 + 0], acc0, 0, 0, 0);
                acc1 = __builtin_amdgcn_mfma_f32_16x16x32_bf16(ha1[kb], bw[kb * 4 + 1], acc1, 0, 0, 0);
                acc2 = __builtin_amdgcn_mfma_f32_16x16x32_bf16(ha1[kb], bw[kb * 4 + 2], acc2, 0, 0, 0);
                acc3 = __builtin_amdgcn_mfma_f32_16x16x32_bf16(ha1[kb], bw[kb * 4 + 3], acc3, 0, 0, 0);
            }
            // Wi1 x h0(t) (B-fragments from LDS)
#pragma unroll
            for (int kb = 0; kb < 16; ++kb) {
                const char* base = (const char*)wi_lds + (kb << 12) + wbase;
                short8 w0 = *(const short8*)(base);
                short8 w1 = *(const short8*)(base + (1 << 10));
                short8 w2 = *(const short8*)(base + (2 << 10));
                short8 w3 = *(const short8*)(base + (3 << 10));
                acc0 = __builtin_amdgcn_mfma_f32_16x16x32_bf16(ha0[kb], w0, acc0, 0, 0, 0);
                acc1 = __builtin_amdgcn_mfma_f32_16x16x32_bf16(ha0[kb], w1, acc1, 0, 0, 0);
                acc2 = __builtin_amdgcn_mfma_f32_16x16x32_bf16(ha0[kb], w2, acc2, 0, 0, 0);
                acc3 = __builtin_amdgcn_mfma_f32_16x16x32_bf16(ha0[kb], w3, acc3, 0, 0, 0);
            }

            float hvv[4];
#pragma unroll
            for (int r = 0; r < 4; ++r) {
                int b = m0 + (quad << 2) + r;
                int jj = j0 + l15;
                float iv = sigm(acc0[r] + gb0);
                float fv = sigm(acc1[r] + gb1);
                float gg = tanh_f(acc2[r] + gb2);
                float ov = sigm(acc3[r] + gb3);
                float cn = fv * cc[r] + iv * gg;
                cc[r] = cn;
                float hv = ov * tanh_f(cn);
                hvv[r] = hv;
                unsigned short hb16 = f2bf(hv);
                unsigned packed = (unsigned)hb16 |
                                  (((unsigned)(unsigned short)__shfl_xor((int)hb16, 1)) << 16);
                if (!(l15 & 1))
                    store_coh(&h1h[((size_t)(t + 1) << 14) + (b << 8) + (jj >> 1)], packed);
            }

            // publish h1(t); out-stores + tail-stores overlap the poll
            flag_publish(flag1, slot, (unsigned)(t + 2));
#pragma unroll
            for (int r = 0; r < 4; ++r) {
                int b = m0 + (quad << 2) + r;
                int jj = j0 + l15;
                out[((size_t)((b << 8) + t)) * H_ + jj] = hvv[r];
            }
            if (t == T_ - 1) {
#pragma unroll
                for (int r = 0; r < 4; ++r) {
                    int b = m0 + (quad << 2) + r;
                    int jj = j0 + l15;
                    hT[BH + ((size_t)b << 9) + jj] = hvv[r];
                    cT[BH + ((size_t)b << 9) + jj] = cc[r];
                }
            }
            flag_wait(flag1, (unsigned)(t + 2));

            if (t < T_ - 1) {
                // h1(t) fragments from slot t+1 (just published by cohort)
                const unsigned* ap1 =
                    h1h + ((size_t)(t + 1) << 14) + ((m0 + l15) << 8) + (quad << 2);
#pragma unroll
                for (int kb = 0; kb < 16; ++kb) ha1[kb] = *(const short8*)(ap1 + (kb << 4));
                // h0(t+1) from slot t+2 (layer 0 runs ahead: wait is ~instant)
                flag_wait(flag0, (unsigned)(t + 3));
                const unsigned* ap0 =
                    h0h + ((size_t)(t + 2) << 14) + ((m0 + l15) << 8) + (quad << 2);
#pragma unroll
                for (int kb = 0; kb < 16; ++kb) ha0[kb] = *(const short8*)(ap0 + (kb << 4));
            }
        }
    }
}

extern "C" void kernel_launch(void* const* d_in, const int* in_sizes, int n_in,
                              void* d_out, int out_size, void* d_ws, size_t ws_size,
                              hipStream_t stream) {
    const float* x  = (const float*)d_in[0];
    const float* Wi = (const float*)d_in[1];
    const float* Wh = (const float*)d_in[2];
    const float* bi = (const float*)d_in[3];
    const float* bh = (const float*)d_in[4];
    float* out = (float*)d_out;

    char* w = (char*)d_ws;
    const size_t NK = (size_t)NG * H_;
    unsigned short* Wt  = (unsigned short*)w;                  // 8 MB (4 slabs)
    unsigned short* xb  = Wt + 4 * NK;                         // 16 MB
    unsigned short* Gi  = xb + (size_t)16384 * H_;             // 64 MB (layer-0 gates)
    unsigned* h0h       = (unsigned*)(Gi + (size_t)16384 * NG);// (T+1)*64*256 u32 = 16.85 MB
    unsigned* h1h       = h0h + (size_t)(T_ + 1) * 16384;      // 16.85 MB
    unsigned* flags     = h1h + (size_t)(T_ + 1) * 16384;      // 64 words

    hipMemsetAsync(flags, 0, 256, stream);

    transpose_cvt<<<dim3(8, 32, 4), 256, 0, stream>>>(Wi, Wh, Wt);
    cvt_bf16<<<8192, 256, 0, stream>>>(x, xb);

    // layer-0 input gates (bulk GEMM, biases baked in)
    gemm_bt<<<dim3(256, 32), 256, 0, stream>>>(xb, Wt + 0 * NK, bi, bh, Gi);

    // fused pipelined 2-layer recurrence
    lstm_fused<<<64, 256, 0, stream>>>(Gi, Wt, h0h, h1h, bi, bh,
                                       out, out + BTH, out + BTH + 2 * (size_t)BH, flags);
}

// Round 5
// 2344.499 us; speedup vs baseline: 2.3747x; 1.0651x over previous
//
#include <hip/hip_runtime.h>

typedef __attribute__((ext_vector_type(8))) short short8;
typedef __attribute__((ext_vector_type(4))) float f32x4;
typedef __attribute__((ext_vector_type(4))) int   i32x4;
typedef __attribute__((ext_vector_type(4))) float fvec4;
typedef __attribute__((ext_vector_type(4))) unsigned short u16x4;

#define B_ 64
#define T_ 256
#define H_ 512
#define NG 2048   // 4*H
#define BTH (64*256*512)
#define BH (64*512)
#define FPAD 64   // flag padding: 64 dwords = 256B per flag -> distinct L3 lines/channels

__device__ __forceinline__ float bf2f(unsigned short u) {
    return __builtin_bit_cast(float, ((unsigned)u) << 16);
}
__device__ __forceinline__ unsigned short f2bf(float f) {
    unsigned u = __builtin_bit_cast(unsigned, f);
    u += 0x7fffu + ((u >> 16) & 1u);   // RNE
    return (unsigned short)(u >> 16);
}
__device__ __forceinline__ float sigm(float x) { return 1.f / (1.f + __expf(-x)); }
__device__ __forceinline__ float tanh_f(float x) {
    x = fminf(15.f, fmaxf(-15.f, x));
    float e = __expf(-2.f * x);
    return (1.f - e) / (1.f + e);
}

__device__ __forceinline__ void store_coh(unsigned* p, unsigned v) {
    __hip_atomic_store(p, v, __ATOMIC_RELAXED, __HIP_MEMORY_SCOPE_AGENT);
}

// ---------------- prep: weight transpose f32[K,N] -> bf16[N,K] ----------------
__global__ void transpose_cvt(const float* __restrict__ Wi, const float* __restrict__ Wh,
                              unsigned short* __restrict__ Wt) {
    __shared__ float tile[64][65];
    int z = blockIdx.z;
    const float* src = (z < 2 ? Wi : Wh) + (size_t)(z & 1) * H_ * NG;
    unsigned short* dst = Wt + (size_t)z * NG * H_;
    int k0 = blockIdx.x * 64, n0 = blockIdx.y * 64;
    int tx = threadIdx.x & 63, ty = threadIdx.x >> 6;
#pragma unroll
    for (int p = 0; p < 16; ++p) {
        int r = (p << 2) + ty;
        tile[r][tx] = src[(size_t)(k0 + r) * NG + n0 + tx];
    }
    __syncthreads();
#pragma unroll
    for (int p = 0; p < 16; ++p) {
        int r = (p << 2) + ty;
        dst[(size_t)(n0 + r) * H_ + k0 + tx] = f2bf(tile[tx][r]);
    }
}

__global__ void cvt_bf16(const float* __restrict__ x, unsigned short* __restrict__ xb) {
    size_t i = ((size_t)blockIdx.x * 256 + threadIdx.x) * 4;
    fvec4 v = *(const fvec4*)&x[i];
    u16x4 o;
    o[0] = f2bf(v[0]); o[1] = f2bf(v[1]); o[2] = f2bf(v[2]); o[3] = f2bf(v[3]);
    *(u16x4*)&xb[i] = o;
}

// ---------------- big GEMM (layer-0 input gates only) ----------------
__global__ __launch_bounds__(256) void gemm_bt(
    const unsigned short* __restrict__ A, const unsigned short* __restrict__ Bt,
    const float* __restrict__ bias1, const float* __restrict__ bias2,
    unsigned short* __restrict__ C) {
    const int tid = threadIdx.x;
    const int wave = tid >> 6, lane = tid & 63;
    const int quad = lane >> 4, l15 = lane & 15;
    const int row0 = blockIdx.x * 64 + wave * 16;
    const int col0 = blockIdx.y * 64;
    f32x4 acc[4] = {};
    const unsigned short* ap = A + (size_t)(row0 + l15) * H_ + (quad << 3);
    const unsigned short* bp = Bt + (size_t)(col0 + l15) * H_ + (quad << 3);
#pragma unroll
    for (int kk = 0; kk < H_; kk += 32) {
        short8 a = *(const short8*)(ap + kk);
#pragma unroll
        for (int c4 = 0; c4 < 4; ++c4) {
            short8 b = *(const short8*)(bp + (size_t)(c4 << 4) * H_ + kk);
            acc[c4] = __builtin_amdgcn_mfma_f32_16x16x32_bf16(a, b, acc[c4], 0, 0, 0);
        }
    }
#pragma unroll
    for (int c4 = 0; c4 < 4; ++c4) {
        int col = col0 + (c4 << 4) + l15;
        float bs = bias1[col] + bias2[col];
#pragma unroll
        for (int r = 0; r < 4; ++r) {
            int row = row0 + (quad << 2) + r;
            int t = row & 255, b = row >> 8;
            C[((size_t)t * B_ + b) * NG + col] = f2bf(acc[c4][r] + bs);
        }
    }
}

// ---------------- distributed-flag barrier: padded flags, wave-0-only poll ------
// publish: __syncthreads drains all waves' sc1 data stores (vmcnt 0) BEFORE the
// flag store. Independent memory ops go between publish and wait to overlap poll.
// Only wave 0 polls (32 padded flags -> 32 distinct L3 lines); waves 1-3 are
// released by the trailing __syncthreads (also the compiler memory barrier).
__device__ __forceinline__ void flag_publish(unsigned* flags, int myslot, unsigned target) {
    __syncthreads();
    if (threadIdx.x == 0) store_coh(flags + myslot * FPAD, target);
}
__device__ __forceinline__ void flag_wait_w0(const unsigned* flags, unsigned target) {
    if (threadIdx.x < 64) {
        int spins = 0;
        for (;;) {
            unsigned v = __hip_atomic_load(flags + (threadIdx.x & 31) * FPAD,
                                           __ATOMIC_RELAXED, __HIP_MEMORY_SCOPE_AGENT);
            if (__all((int)(v >= target))) break;
            __builtin_amdgcn_s_sleep(1);
            if (++spins > 400000) break;   // failsafe: wrong answer, not hang
        }
    }
    __syncthreads();
}
// dual wait in ONE poll round: lanes 0..31 check fA >= tgtA, lanes 32..63 check fB >= tgtB
__device__ __forceinline__ void flag_wait2_w0(const unsigned* fA, unsigned tgtA,
                                              const unsigned* fB, unsigned tgtB) {
    if (threadIdx.x < 64) {
        const unsigned* p = (threadIdx.x < 32) ? fA + threadIdx.x * FPAD
                                               : fB + (threadIdx.x & 31) * FPAD;
        unsigned tgt = (threadIdx.x < 32) ? tgtA : tgtB;
        int spins = 0;
        for (;;) {
            unsigned v = __hip_atomic_load(p, __ATOMIC_RELAXED, __HIP_MEMORY_SCOPE_AGENT);
            if (__all((int)(v >= tgt))) break;
            __builtin_amdgcn_s_sleep(1);
            if (++spins > 400000) break;
        }
    }
    __syncthreads();
}

// ---------------- fused persistent 2-layer recurrent kernel ----------------
// 64 WGs x 256 thr. WGs 0..31: layer 0; WGs 32..63: layer 1 (lags ~1 step).
// BOTH h0 and h1 go through write-once history buffers (plain vectorized loads
// are coherence-safe: fresh addresses each step). Producers store with sc1;
// visibility ordered by syncthreads-drain -> flag store -> wave-0 poll -> sync.
__global__ __launch_bounds__(256, 1) void lstm_fused(
    const unsigned short* __restrict__ Gi,   // [T][B][2048] bf16 (layer-0 gates incl. biases)
    const unsigned short* __restrict__ Wt,   // 4 slabs: Wi0^T, Wi1^T, Wh0^T, Wh1^T  [2048][512] bf16
    unsigned* __restrict__ h0h,              // [T+1][64][256] u32-packed bf16 h0 history
    unsigned* __restrict__ h1h,              // [T+1][64][256] u32-packed bf16 h1 history
    const float* __restrict__ bi, const float* __restrict__ bh,
    float* __restrict__ out,                 // [B][T][512] f32 (layer-1 output)
    float* __restrict__ hT, float* __restrict__ cT,   // [L][B][512]
    unsigned* __restrict__ flags) {          // padded: [0..31]*FPAD=layer0, +32*FPAD=layer1
    __shared__ unsigned short wi_lds[64 * 512];   // 64KB, fragment-linear layout
    const size_t NK = (size_t)NG * H_;
    const int tid = threadIdx.x;
    const int wave = tid >> 6, lane = tid & 63;
    const int quad = lane >> 4, l15 = lane & 15;
    const int m0 = wave << 4;
    unsigned* flag0 = flags;
    unsigned* flag1 = flags + 32 * FPAD;

    if (blockIdx.x < 32) {
        // ================= layer 0 =================
        const int slot = (int)blockIdx.x;
        const int j0 = slot << 4;
        const unsigned short* Wht = Wt + 2 * NK;
        short8 bw[64];
#pragma unroll
        for (int kb = 0; kb < 16; ++kb)
#pragma unroll
            for (int g = 0; g < 4; ++g)
                bw[kb * 4 + g] =
                    *(const short8*)&Wht[(size_t)((g << 9) + j0 + l15) * H_ + (kb << 5) + (quad << 3)];
#pragma unroll
        for (int i = 0; i < 64; ++i) asm volatile("" : "+v"(bw[i]));

        // zero h0 history slot 0 (own 16 cols, all 64 rows via 4 waves)
        if (!(l15 & 1)) {
#pragma unroll
            for (int r = 0; r < 4; ++r) {
                int b = m0 + (quad << 2) + r;
                store_coh(&h0h[(b << 8) + ((j0 + l15) >> 1)], 0u);
            }
        }
        float cc[4] = {0.f, 0.f, 0.f, 0.f};

        flag_publish(flag0, slot, 1u);
        // Gi[0] prefetch in the publish/wait gap
        float gv[4][4];
#pragma unroll
        for (int r = 0; r < 4; ++r) {
            int b = m0 + (quad << 2) + r;
#pragma unroll
            for (int g = 0; g < 4; ++g)
                gv[g][r] = bf2f(Gi[(size_t)b * NG + (g << 9) + j0 + l15]);
        }
        flag_wait_w0(flag0, 1u);

        for (int t = 0; t < T_; ++t) {
            // h(t-1) fragments: plain vectorized loads from write-once history
            const unsigned* ap = h0h + ((size_t)t << 14) + ((m0 + l15) << 8) + (quad << 2);
            short8 ha[16];
#pragma unroll
            for (int kb = 0; kb < 16; ++kb) ha[kb] = *(const short8*)(ap + (kb << 4));

            f32x4 acc0 = {}, acc1 = {}, acc2 = {}, acc3 = {};
#pragma unroll
            for (int kb = 0; kb < 16; ++kb) {
                acc0 = __builtin_amdgcn_mfma_f32_16x16x32_bf16(ha[kb], bw[kb * 4 + 0], acc0, 0, 0, 0);
                acc1 = __builtin_amdgcn_mfma_f32_16x16x32_bf16(ha[kb], bw[kb * 4 + 1], acc1, 0, 0, 0);
                acc2 = __builtin_amdgcn_mfma_f32_16x16x32_bf16(ha[kb], bw[kb * 4 + 2], acc2, 0, 0, 0);
                acc3 = __builtin_amdgcn_mfma_f32_16x16x32_bf16(ha[kb], bw[kb * 4 + 3], acc3, 0, 0, 0);
            }

            float hvv[4];
#pragma unroll
            for (int r = 0; r < 4; ++r) {
                int b = m0 + (quad << 2) + r;
                int jj = j0 + l15;
                float iv = sigm(acc0[r] + gv[0][r]);
                float fv = sigm(acc1[r] + gv[1][r]);
                float gg = tanh_f(acc2[r] + gv[2][r]);
                float ov = sigm(acc3[r] + gv[3][r]);
                float cn = fv * cc[r] + iv * gg;
                cc[r] = cn;
                float hv = ov * tanh_f(cn);
                hvv[r] = hv;
                unsigned short hb16 = f2bf(hv);
                unsigned packed = (unsigned)hb16 |
                                  (((unsigned)(unsigned short)__shfl_xor((int)hb16, 1)) << 16);
                if (!(l15 & 1))
                    store_coh(&h0h[((size_t)(t + 1) << 14) + (b << 8) + (jj >> 1)], packed);
            }

            // publish h0(t); prefetch Gi[t+1] + tail stores while peers converge
            flag_publish(flag0, slot, (unsigned)(t + 2));
            int tn = (t + 1) & (T_ - 1);
            float gn[4][4];
#pragma unroll
            for (int r = 0; r < 4; ++r) {
                int b = m0 + (quad << 2) + r;
#pragma unroll
                for (int g = 0; g < 4; ++g)
                    gn[g][r] = bf2f(Gi[((size_t)tn * B_ + b) * NG + (g << 9) + j0 + l15]);
            }
            if (t == T_ - 1) {
#pragma unroll
                for (int r = 0; r < 4; ++r) {
                    int b = m0 + (quad << 2) + r;
                    int jj = j0 + l15;
                    hT[((size_t)b << 9) + jj] = hvv[r];
                    cT[((size_t)b << 9) + jj] = cc[r];
                }
            }
            flag_wait_w0(flag0, (unsigned)(t + 2));
#pragma unroll
            for (int r = 0; r < 4; ++r)
#pragma unroll
                for (int g = 0; g < 4; ++g) gv[g][r] = gn[g][r];
        }
    } else {
        // ================= layer 1 =================
        const int slot = (int)blockIdx.x - 32;
        const int j0 = slot << 4;
        const unsigned short* Wht = Wt + 3 * NK;
        short8 bw[64];
#pragma unroll
        for (int kb = 0; kb < 16; ++kb)
#pragma unroll
            for (int g = 0; g < 4; ++g)
                bw[kb * 4 + g] =
                    *(const short8*)&Wht[(size_t)((g << 9) + j0 + l15) * H_ + (kb << 5) + (quad << 3)];
#pragma unroll
        for (int i = 0; i < 64; ++i) asm volatile("" : "+v"(bw[i]));

        // stage Wi1 slab into LDS, fragment-linear:
        //   byte = kb*4096 + g*1024 + quad*256 + l15*16
        const unsigned short* Wit = Wt + 1 * NK;
#pragma unroll
        for (int i2 = 0; i2 < 16; ++i2) {
            int c = i2 * 256 + tid;            // 4096 x 16B chunks
            int l = c & 15, q = (c >> 4) & 3, g = (c >> 6) & 3, kb = c >> 8;
            short8 v = *(const short8*)&Wit[(size_t)((g << 9) + j0 + l) * H_ + (kb << 5) + (q << 3)];
            *(short8*)((char*)wi_lds + ((size_t)c << 4)) = v;
        }
        const int wbase = (quad << 8) + (l15 << 4);

        float gb0 = bi[NG + j0 + l15]        + bh[NG + j0 + l15];
        float gb1 = bi[NG + 512 + j0 + l15]  + bh[NG + 512 + j0 + l15];
        float gb2 = bi[NG + 1024 + j0 + l15] + bh[NG + 1024 + j0 + l15];
        float gb3 = bi[NG + 1536 + j0 + l15] + bh[NG + 1536 + j0 + l15];

        // zero own h1 history slot 0
        if (!(l15 & 1)) {
#pragma unroll
            for (int r = 0; r < 4; ++r) {
                int b = m0 + (quad << 2) + r;
                store_coh(&h1h[(b << 8) + ((j0 + l15) >> 1)], 0u);
            }
        }
        float cc[4] = {0.f, 0.f, 0.f, 0.f};
        flag_publish(flag1, slot, 1u);   // covers LDS staging + h1 zero-init
        // combined wait: own cohort ready AND h0(0) visible (one poll round)
        flag_wait2_w0(flag1, 1u, flag0, 2u);

        // prefetch h1(-1) from slot 0 and h0(0) from slot 1 (both plain b128)
        short8 ha1[16], ha0[16];
        {
            const unsigned* ap1 = h1h + ((m0 + l15) << 8) + (quad << 2);
#pragma unroll
            for (int kb = 0; kb < 16; ++kb) ha1[kb] = *(const short8*)(ap1 + (kb << 4));
            const unsigned* ap0 = h0h + ((size_t)1 << 14) + ((m0 + l15) << 8) + (quad << 2);
#pragma unroll
            for (int kb = 0; kb < 16; ++kb) ha0[kb] = *(const short8*)(ap0 + (kb << 4));
        }

        for (int t = 0; t < T_; ++t) {
            f32x4 acc0 = {}, acc1 = {}, acc2 = {}, acc3 = {};
            // Wh1 x h1(t-1)
#pragma unroll
            for (int kb = 0; kb < 16; ++kb) {
                acc0 = __builtin_amdgcn_mfma_f32_16x16x32_bf16(ha1[kb], bw[kb * 4 + 0], acc0, 0, 0, 0);
                acc1 = __builtin_amdgcn_mfma_f32_16x16x32_bf16(ha1[kb], bw[kb * 4 + 1], acc1, 0, 0, 0);
                acc2 = __builtin_amdgcn_mfma_f32_16x16x32_bf16(ha1[kb], bw[kb * 4 + 2], acc2, 0, 0, 0);
                acc3 = __builtin_amdgcn_mfma_f32_16x16x32_bf16(ha1[kb], bw[kb * 4 + 3], acc3, 0, 0, 0);
            }
            // Wi1 x h0(t) (B-fragments from LDS)
#pragma unroll
            for (int kb = 0; kb < 16; ++kb) {
                const char* base = (const char*)wi_lds + (kb << 12) + wbase;
                short8 w0 = *(const short8*)(base);
                short8 w1 = *(const short8*)(base + (1 << 10));
                short8 w2 = *(const short8*)(base + (2 << 10));
                short8 w3 = *(const short8*)(base + (3 << 10));
                acc0 = __builtin_amdgcn_mfma_f32_16x16x32_bf16(ha0[kb], w0, acc0, 0, 0, 0);
                acc1 = __builtin_amdgcn_mfma_f32_16x16x32_bf16(ha0[kb], w1, acc1, 0, 0, 0);
                acc2 = __builtin_amdgcn_mfma_f32_16x16x32_bf16(ha0[kb], w2, acc2, 0, 0, 0);
                acc3 = __builtin_amdgcn_mfma_f32_16x16x32_bf16(ha0[kb], w3, acc3, 0, 0, 0);
            }

            float hvv[4];
#pragma unroll
            for (int r = 0; r < 4; ++r) {
                int b = m0 + (quad << 2) + r;
                int jj = j0 + l15;
                float iv = sigm(acc0[r] + gb0);
                float fv = sigm(acc1[r] + gb1);
                float gg = tanh_f(acc2[r] + gb2);
                float ov = sigm(acc3[r] + gb3);
                float cn = fv * cc[r] + iv * gg;
                cc[r] = cn;
                float hv = ov * tanh_f(cn);
                hvv[r] = hv;
                unsigned short hb16 = f2bf(hv);
                unsigned packed = (unsigned)hb16 |
                                  (((unsigned)(unsigned short)__shfl_xor((int)hb16, 1)) << 16);
                if (!(l15 & 1))
                    store_coh(&h1h[((size_t)(t + 1) << 14) + (b << 8) + (jj >> 1)], packed);
            }

            // publish h1(t); out-stores + tail-stores overlap the poll
            flag_publish(flag1, slot, (unsigned)(t + 2));
#pragma unroll
            for (int r = 0; r < 4; ++r) {
                int b = m0 + (quad << 2) + r;
                int jj = j0 + l15;
                out[((size_t)((b << 8) + t)) * H_ + jj] = hvv[r];
            }
            if (t == T_ - 1) {
#pragma unroll
                for (int r = 0; r < 4; ++r) {
                    int b = m0 + (quad << 2) + r;
                    int jj = j0 + l15;
                    hT[BH + ((size_t)b << 9) + jj] = hvv[r];
                    cT[BH + ((size_t)b << 9) + jj] = cc[r];
                }
            }
            // combined wait: cohort h1(t) visible AND layer-0 h0(t+1) visible
            unsigned tgt0 = (unsigned)(t + 3);
            if (tgt0 > (unsigned)(T_ + 1)) tgt0 = (unsigned)(T_ + 1);
            flag_wait2_w0(flag1, (unsigned)(t + 2), flag0, tgt0);

            if (t < T_ - 1) {
                // h1(t) fragments from slot t+1 (just published by cohort)
                const unsigned* ap1 =
                    h1h + ((size_t)(t + 1) << 14) + ((m0 + l15) << 8) + (quad << 2);
#pragma unroll
                for (int kb = 0; kb < 16; ++kb) ha1[kb] = *(const short8*)(ap1 + (kb << 4));
                // h0(t+1) from slot t+2 (layer 0 runs ahead: already confirmed)
                const unsigned* ap0 =
                    h0h + ((size_t)(t + 2) << 14) + ((m0 + l15) << 8) + (quad << 2);
#pragma unroll
                for (int kb = 0; kb < 16; ++kb) ha0[kb] = *(const short8*)(ap0 + (kb << 4));
            }
        }
    }
}

extern "C" void kernel_launch(void* const* d_in, const int* in_sizes, int n_in,
                              void* d_out, int out_size, void* d_ws, size_t ws_size,
                              hipStream_t stream) {
    const float* x  = (const float*)d_in[0];
    const float* Wi = (const float*)d_in[1];
    const float* Wh = (const float*)d_in[2];
    const float* bi = (const float*)d_in[3];
    const float* bh = (const float*)d_in[4];
    float* out = (float*)d_out;

    char* w = (char*)d_ws;
    const size_t NK = (size_t)NG * H_;
    unsigned short* Wt  = (unsigned short*)w;                  // 8 MB (4 slabs)
    unsigned short* xb  = Wt + 4 * NK;                         // 16 MB
    unsigned short* Gi  = xb + (size_t)16384 * H_;             // 64 MB (layer-0 gates)
    unsigned* h0h       = (unsigned*)(Gi + (size_t)16384 * NG);// (T+1)*64*256 u32 = 16.85 MB
    unsigned* h1h       = h0h + (size_t)(T_ + 1) * 16384;      // 16.85 MB
    unsigned* flags     = h1h + (size_t)(T_ + 1) * 16384;      // 64 slots * 256B = 16 KB

    hipMemsetAsync(flags, 0, 64 * FPAD * sizeof(unsigned), stream);

    transpose_cvt<<<dim3(8, 32, 4), 256, 0, stream>>>(Wi, Wh, Wt);
    cvt_bf16<<<8192, 256, 0, stream>>>(x, xb);

    // layer-0 input gates (bulk GEMM, biases baked in)
    gemm_bt<<<dim3(256, 32), 256, 0, stream>>>(xb, Wt + 0 * NK, bi, bh, Gi);

    // fused pipelined 2-layer recurrence
    lstm_fused<<<64, 256, 0, stream>>>(Gi, Wt, h0h, h1h, bi, bh,
                                       out, out + BTH, out + BTH + 2 * (size_t)BH, flags);
}

// Round 7
// 2137.306 us; speedup vs baseline: 2.6049x; 1.0969x over previous
//
#include <hip/hip_runtime.h>

typedef __attribute__((ext_vector_type(8))) short short8;
typedef __attribute__((ext_vector_type(4))) float f32x4;
typedef __attribute__((ext_vector_type(4))) float fvec4;
typedef __attribute__((ext_vector_type(4))) unsigned short u16x4;

#define B_ 64
#define T_ 256
#define H_ 512
#define NG 2048   // 4*H
#define BTH (64*256*512)
#define BH (64*512)
#define FPAD 64   // 256B per flag slot -> distinct L3 lines

__device__ __forceinline__ float bf2f(unsigned short u) {
    return __builtin_bit_cast(float, ((unsigned)u) << 16);
}
__device__ __forceinline__ unsigned short f2bf(float f) {
    unsigned u = __builtin_bit_cast(unsigned, f);
    u += 0x7fffu + ((u >> 16) & 1u);   // RNE
    return (unsigned short)(u >> 16);
}
__device__ __forceinline__ float sigm(float x) { return 1.f / (1.f + __expf(-x)); }
__device__ __forceinline__ float tanh_f(float x) {
    x = fminf(15.f, fmaxf(-15.f, x));
    float e = __expf(-2.f * x);
    return (1.f - e) / (1.f + e);
}

__device__ __forceinline__ void store_coh(unsigned* p, unsigned v) {
    __hip_atomic_store(p, v, __ATOMIC_RELAXED, __HIP_MEMORY_SCOPE_AGENT);
}
// drain this wave's outstanding vmem ops (stores acked at coherence point)
__device__ __forceinline__ void drain_vm() {
    asm volatile("s_waitcnt vmcnt(0)" ::: "memory");
}
// wave-cohort wait: poll the 32 flags of wave-index w across the 32 WG slots.
// No barrier, no vmcnt drain: pre-issued data loads stay in flight.
__device__ __forceinline__ void wv_wait(const unsigned* fl, int w, unsigned target) {
    const unsigned* p = fl + (size_t)(((threadIdx.x & 31) << 2) + w) * FPAD;
    int spins = 0;
    for (;;) {
        unsigned v = __hip_atomic_load(p, __ATOMIC_RELAXED, __HIP_MEMORY_SCOPE_AGENT);
        if (__all((int)(v >= target))) break;
        __builtin_amdgcn_s_sleep(1);
        if (++spins > 400000) break;   // failsafe: wrong answer, not hang
    }
    asm volatile("" ::: "memory");     // no hoisting of data loads above the poll
}

// ---------------- prep: weight transpose f32[K,N] -> bf16[N,K] ----------------
__global__ void transpose_cvt(const float* __restrict__ Wi, const float* __restrict__ Wh,
                              unsigned short* __restrict__ Wt) {
    __shared__ float tile[64][65];
    int z = blockIdx.z;
    const float* src = (z < 2 ? Wi : Wh) + (size_t)(z & 1) * H_ * NG;
    unsigned short* dst = Wt + (size_t)z * NG * H_;
    int k0 = blockIdx.x * 64, n0 = blockIdx.y * 64;
    int tx = threadIdx.x & 63, ty = threadIdx.x >> 6;
#pragma unroll
    for (int p = 0; p < 16; ++p) {
        int r = (p << 2) + ty;
        tile[r][tx] = src[(size_t)(k0 + r) * NG + n0 + tx];
    }
    __syncthreads();
#pragma unroll
    for (int p = 0; p < 16; ++p) {
        int r = (p << 2) + ty;
        dst[(size_t)(n0 + r) * H_ + k0 + tx] = f2bf(tile[tx][r]);
    }
}

__global__ void cvt_bf16(const float* __restrict__ x, unsigned short* __restrict__ xb) {
    size_t i = ((size_t)blockIdx.x * 256 + threadIdx.x) * 4;
    fvec4 v = *(const fvec4*)&x[i];
    u16x4 o;
    o[0] = f2bf(v[0]); o[1] = f2bf(v[1]); o[2] = f2bf(v[2]); o[3] = f2bf(v[3]);
    *(u16x4*)&xb[i] = o;
}

// ---------------- big GEMM (layer-0 input gates), blocked Gi output ------------
// Gi2 u16 index = ((blk*256 + t)*4 + g)*1024 + b*16 + cl   (blk=(col&511)>>4, cl=col&15)
// -> each recurrent WG's per-step slice is 8KB in 4 contiguous 2KB chunks: exact fetch.
__global__ __launch_bounds__(256) void gemm_bt(
    const unsigned short* __restrict__ A, const unsigned short* __restrict__ Bt,
    const float* __restrict__ bias1, const float* __restrict__ bias2,
    unsigned short* __restrict__ C) {
    const int tid = threadIdx.x;
    const int wave = tid >> 6, lane = tid & 63;
    const int quad = lane >> 4, l15 = lane & 15;
    const int row0 = blockIdx.x * 64 + wave * 16;
    const int col0 = blockIdx.y * 64;
    f32x4 acc[4] = {};
    const unsigned short* ap = A + (size_t)(row0 + l15) * H_ + (quad << 3);
    const unsigned short* bp = Bt + (size_t)(col0 + l15) * H_ + (quad << 3);
#pragma unroll
    for (int kk = 0; kk < H_; kk += 32) {
        short8 a = *(const short8*)(ap + kk);
#pragma unroll
        for (int c4 = 0; c4 < 4; ++c4) {
            short8 b = *(const short8*)(bp + (size_t)(c4 << 4) * H_ + kk);
            acc[c4] = __builtin_amdgcn_mfma_f32_16x16x32_bf16(a, b, acc[c4], 0, 0, 0);
        }
    }
#pragma unroll
    for (int c4 = 0; c4 < 4; ++c4) {
        int col = col0 + (c4 << 4) + l15;
        float bs = bias1[col] + bias2[col];
        int g = col >> 9;
        int blk = (col & 511) >> 4;
#pragma unroll
        for (int r = 0; r < 4; ++r) {
            int row = row0 + (quad << 2) + r;
            int t = row & 255, b = row >> 8;
            C[((size_t)blk << 20) + ((size_t)t << 12) + (g << 10) + (b << 4) + l15] =
                f2bf(acc[c4][r] + bs);
        }
    }
}

// ---------------- fused persistent 2-layer recurrent kernel ----------------
// 64 WGs x 256 thr. WGs 0..31: layer 0; WGs 32..63: layer 1 (lags >=1 step; h0
// full history means layer 0 NEVER waits on layer 1).
// h layout (slot-major, u32-packed bf16): h[t][slot 0..31][b 0..63][8 u32].
//   writer (WG slot s, wave w): rows [w*16,w*16+16) x 32B -> 512B contiguous/wave.
//   reader (wave w): per-kb load = two fully-coalesced 512B runs.
// Sync: PER-WAVE flags. Producer: sc1 data stores -> s_waitcnt vmcnt(0) ->
// own-flag store. Consumer wave polls only its 32-flag wave cohort (the only
// waves whose rows it reads). No __syncthreads in the steady loop.
__global__ __launch_bounds__(256, 1) void lstm_fused(
    const unsigned short* __restrict__ Gi,   // blocked layer-0 gates (incl. biases)
    const unsigned short* __restrict__ Wt,   // 4 slabs: Wi0^T, Wi1^T, Wh0^T, Wh1^T
    unsigned* __restrict__ h0h,              // [T+1][32][64][8] u32 h0 history
    unsigned* __restrict__ h1h,              // [T+1][32][64][8] u32 h1 history
    const float* __restrict__ bi, const float* __restrict__ bh,
    float* __restrict__ out,                 // [B][T][512] f32 (layer-1 output)
    float* __restrict__ hT, float* __restrict__ cT,   // [L][B][512]
    unsigned* __restrict__ flags) {          // [layer][slot*4+wave]*FPAD
    __shared__ unsigned short wi_lds[64 * 512];   // 64KB, fragment-linear layout
    const size_t NK = (size_t)NG * H_;
    const int tid = threadIdx.x;
    const int wave = tid >> 6, lane = tid & 63;
    const int quad = lane >> 4, l15 = lane & 15;
    const int m0 = wave << 4;
    unsigned* flag0 = flags;
    unsigned* flag1 = flags + 128 * FPAD;
    // per-lane offset into a t-slab of the h history (reader side)
    const size_t hoff = ((size_t)(quad >> 1) << 9) + ((size_t)(m0 + l15) << 3) + ((quad & 1) << 2);

    if (blockIdx.x < 32) {
        // ================= layer 0 =================
        const int slot = (int)blockIdx.x;
        const int j0 = slot << 4;
        const unsigned short* Wht = Wt + 2 * NK;
        short8 bw[64];
#pragma unroll
        for (int kb = 0; kb < 16; ++kb)
#pragma unroll
            for (int g = 0; g < 4; ++g)
                bw[kb * 4 + g] =
                    *(const short8*)&Wht[(size_t)((g << 9) + j0 + l15) * H_ + (kb << 5) + (quad << 3)];
#pragma unroll
        for (int i = 0; i < 64; ++i) asm volatile("" : "+v"(bw[i]));

        // zero own rows of h0 slot 0 (contiguous slot-major layout)
        if (!(l15 & 1)) {
            unsigned* hz = h0h + ((size_t)(slot * 64) << 3) + (l15 >> 1);
#pragma unroll
            for (int r = 0; r < 4; ++r)
                store_coh(&hz[(size_t)(m0 + (quad << 2) + r) << 3], 0u);
        }
        float cc[4] = {0.f, 0.f, 0.f, 0.f};
        drain_vm();
        store_coh(&flag0[(size_t)((slot << 2) + wave) * FPAD], 1u);

        // preload Gi[0] (blocked layout; consumed at elementwise of t=0)
        float gv[4][4];
#pragma unroll
        for (int r = 0; r < 4; ++r) {
            int b = m0 + (quad << 2) + r;
#pragma unroll
            for (int g = 0; g < 4; ++g)
                gv[g][r] = bf2f(Gi[((size_t)slot << 20) + (g << 10) + (b << 4) + l15]);
        }

        for (int t = 0; t < T_; ++t) {
            wv_wait(flag0, wave, (unsigned)(t + 1));
            const unsigned* ap = h0h + ((size_t)t << 14) + hoff;
            short8 ha[16];
#pragma unroll
            for (int kb = 0; kb < 16; ++kb) ha[kb] = *(const short8*)(ap + (kb << 10));

            f32x4 acc0 = {}, acc1 = {}, acc2 = {}, acc3 = {};
#pragma unroll
            for (int kb = 0; kb < 16; ++kb) {
                acc0 = __builtin_amdgcn_mfma_f32_16x16x32_bf16(ha[kb], bw[kb * 4 + 0], acc0, 0, 0, 0);
                acc1 = __builtin_amdgcn_mfma_f32_16x16x32_bf16(ha[kb], bw[kb * 4 + 1], acc1, 0, 0, 0);
                acc2 = __builtin_amdgcn_mfma_f32_16x16x32_bf16(ha[kb], bw[kb * 4 + 2], acc2, 0, 0, 0);
                acc3 = __builtin_amdgcn_mfma_f32_16x16x32_bf16(ha[kb], bw[kb * 4 + 3], acc3, 0, 0, 0);
            }

            unsigned* hw = h0h + ((size_t)(t + 1) << 14) + ((size_t)(slot * 64) << 3) + (l15 >> 1);
            float hvv[4];
#pragma unroll
            for (int r = 0; r < 4; ++r) {
                float iv = sigm(acc0[r] + gv[0][r]);
                float fv = sigm(acc1[r] + gv[1][r]);
                float gg = tanh_f(acc2[r] + gv[2][r]);
                float ov = sigm(acc3[r] + gv[3][r]);
                float cn = fv * cc[r] + iv * gg;
                cc[r] = cn;
                float hv = ov * tanh_f(cn);
                hvv[r] = hv;
                unsigned short hb16 = f2bf(hv);
                unsigned packed = (unsigned)hb16 |
                                  (((unsigned)(unsigned short)__shfl_xor((int)hb16, 1)) << 16);
                if (!(l15 & 1))
                    store_coh(&hw[(size_t)(m0 + (quad << 2) + r) << 3], packed);
            }
            if (t == T_ - 1) {
#pragma unroll
                for (int r = 0; r < 4; ++r) {
                    int b = m0 + (quad << 2) + r;
                    int jj = j0 + l15;
                    hT[((size_t)b << 9) + jj] = hvv[r];
                    cT[((size_t)b << 9) + jj] = cc[r];
                }
            }
            drain_vm();   // own h stores acked at coherence point
            store_coh(&flag0[(size_t)((slot << 2) + wave) * FPAD], (unsigned)(t + 2));

            // prefetch Gi[t+1] (latency hidden under next wait/compute)
            int tn = (t + 1) & (T_ - 1);
#pragma unroll
            for (int r = 0; r < 4; ++r) {
                int b = m0 + (quad << 2) + r;
#pragma unroll
                for (int g = 0; g < 4; ++g)
                    gv[g][r] = bf2f(Gi[((size_t)slot << 20) + ((size_t)tn << 12) +
                                       (g << 10) + (b << 4) + l15]);
            }
        }
    } else {
        // ================= layer 1 =================
        const int slot = (int)blockIdx.x - 32;
        const int j0 = slot << 4;
        const unsigned short* Wht = Wt + 3 * NK;
        short8 bw[64];
#pragma unroll
        for (int kb = 0; kb < 16; ++kb)
#pragma unroll
            for (int g = 0; g < 4; ++g)
                bw[kb * 4 + g] =
                    *(const short8*)&Wht[(size_t)((g << 9) + j0 + l15) * H_ + (kb << 5) + (quad << 3)];
#pragma unroll
        for (int i = 0; i < 64; ++i) asm volatile("" : "+v"(bw[i]));

        // stage Wi1 slab into LDS (byte = kb*4096 + g*1024 + quad*256 + l15*16)
        const unsigned short* Wit = Wt + 1 * NK;
#pragma unroll
        for (int i2 = 0; i2 < 16; ++i2) {
            int c = i2 * 256 + tid;            // 4096 x 16B chunks
            int l = c & 15, q = (c >> 4) & 3, g = (c >> 6) & 3, kb = c >> 8;
            short8 v = *(const short8*)&Wit[(size_t)((g << 9) + j0 + l) * H_ + (kb << 5) + (q << 3)];
            *(short8*)((char*)wi_lds + ((size_t)c << 4)) = v;
        }
        __syncthreads();   // one-time: LDS staging visible to all waves
        const int wbase = (quad << 8) + (l15 << 4);

        float gb0 = bi[NG + j0 + l15]        + bh[NG + j0 + l15];
        float gb1 = bi[NG + 512 + j0 + l15]  + bh[NG + 512 + j0 + l15];
        float gb2 = bi[NG + 1024 + j0 + l15] + bh[NG + 1024 + j0 + l15];
        float gb3 = bi[NG + 1536 + j0 + l15] + bh[NG + 1536 + j0 + l15];

        // zero own rows of h1 slot 0
        if (!(l15 & 1)) {
            unsigned* hz = h1h + ((size_t)(slot * 64) << 3) + (l15 >> 1);
#pragma unroll
            for (int r = 0; r < 4; ++r)
                store_coh(&hz[(size_t)(m0 + (quad << 2) + r) << 3], 0u);
        }
        float cc[4] = {0.f, 0.f, 0.f, 0.f};
        drain_vm();
        store_coh(&flag1[(size_t)((slot << 2) + wave) * FPAD], 1u);

        // prologue: h1(-1) from slot 0, h0(0) from slot 1
        short8 ha1[16], ha0[16];
        wv_wait(flag1, wave, 1u);
        {
            const unsigned* ap1 = h1h + hoff;
#pragma unroll
            for (int kb = 0; kb < 16; ++kb) ha1[kb] = *(const short8*)(ap1 + (kb << 10));
        }
        wv_wait(flag0, wave, 2u);
        {
            const unsigned* ap0 = h0h + ((size_t)1 << 14) + hoff;
#pragma unroll
            for (int kb = 0; kb < 16; ++kb) ha0[kb] = *(const short8*)(ap0 + (kb << 10));
        }

        for (int t = 0; t < T_; ++t) {
            f32x4 acc0 = {}, acc1 = {}, acc2 = {}, acc3 = {};
            // Wh1 x h1(t-1) (register B-frags)
#pragma unroll
            for (int kb = 0; kb < 16; ++kb) {
                acc0 = __builtin_amdgcn_mfma_f32_16x16x32_bf16(ha1[kb], bw[kb * 4 + 0], acc0, 0, 0, 0);
                acc1 = __builtin_amdgcn_mfma_f32_16x16x32_bf16(ha1[kb], bw[kb * 4 + 1], acc1, 0, 0, 0);
                acc2 = __builtin_amdgcn_mfma_f32_16x16x32_bf16(ha1[kb], bw[kb * 4 + 2], acc2, 0, 0, 0);
                acc3 = __builtin_amdgcn_mfma_f32_16x16x32_bf16(ha1[kb], bw[kb * 4 + 3], acc3, 0, 0, 0);
            }
            // Wi1 x h0(t) (B-frags from LDS)
#pragma unroll
            for (int kb = 0; kb < 16; ++kb) {
                const char* base = (const char*)wi_lds + (kb << 12) + wbase;
                short8 w0 = *(const short8*)(base);
                short8 w1 = *(const short8*)(base + (1 << 10));
                short8 w2 = *(const short8*)(base + (2 << 10));
                short8 w3 = *(const short8*)(base + (3 << 10));
                acc0 = __builtin_amdgcn_mfma_f32_16x16x32_bf16(ha0[kb], w0, acc0, 0, 0, 0);
                acc1 = __builtin_amdgcn_mfma_f32_16x16x32_bf16(ha0[kb], w1, acc1, 0, 0, 0);
                acc2 = __builtin_amdgcn_mfma_f32_16x16x32_bf16(ha0[kb], w2, acc2, 0, 0, 0);
                acc3 = __builtin_amdgcn_mfma_f32_16x16x32_bf16(ha0[kb], w3, acc3, 0, 0, 0);
            }

            unsigned* hw = h1h + ((size_t)(t + 1) << 14) + ((size_t)(slot * 64) << 3) + (l15 >> 1);
            float hvv[4];
#pragma unroll
            for (int r = 0; r < 4; ++r) {
                float iv = sigm(acc0[r] + gb0);
                float fv = sigm(acc1[r] + gb1);
                float gg = tanh_f(acc2[r] + gb2);
                float ov = sigm(acc3[r] + gb3);
                float cn = fv * cc[r] + iv * gg;
                cc[r] = cn;
                float hv = ov * tanh_f(cn);
                hvv[r] = hv;
                unsigned short hb16 = f2bf(hv);
                unsigned packed = (unsigned)hb16 |
                                  (((unsigned)(unsigned short)__shfl_xor((int)hb16, 1)) << 16);
                if (!(l15 & 1))
                    store_coh(&hw[(size_t)(m0 + (quad << 2) + r) << 3], packed);
            }
            // out stores (plain cached: ack at L2, cheap in the drain)
#pragma unroll
            for (int r = 0; r < 4; ++r) {
                int b = m0 + (quad << 2) + r;
                int jj = j0 + l15;
                out[((size_t)((b << 8) + t)) * H_ + jj] = hvv[r];
            }
            if (t == T_ - 1) {
#pragma unroll
                for (int r = 0; r < 4; ++r) {
                    int b = m0 + (quad << 2) + r;
                    int jj = j0 + l15;
                    hT[BH + ((size_t)b << 9) + jj] = hvv[r];
                    cT[BH + ((size_t)b << 9) + jj] = cc[r];
                }
                break;   // nobody consumes h1(T) / flag1(T+1)
            }
            drain_vm();
            store_coh(&flag1[(size_t)((slot << 2) + wave) * FPAD], (unsigned)(t + 2));

            // h0(t+1): layer 0 runs ahead -> wait ~instant, loads fly during flag1 poll
            wv_wait(flag0, wave, (unsigned)(t + 3));
            const unsigned* ap0 = h0h + ((size_t)(t + 2) << 14) + hoff;
#pragma unroll
            for (int kb = 0; kb < 16; ++kb) ha0[kb] = *(const short8*)(ap0 + (kb << 10));
            // h1(t): own wave-cohort
            wv_wait(flag1, wave, (unsigned)(t + 2));
            const unsigned* ap1 = h1h + ((size_t)(t + 1) << 14) + hoff;
#pragma unroll
            for (int kb = 0; kb < 16; ++kb) ha1[kb] = *(const short8*)(ap1 + (kb << 10));
        }
    }
}

extern "C" void kernel_launch(void* const* d_in, const int* in_sizes, int n_in,
                              void* d_out, int out_size, void* d_ws, size_t ws_size,
                              hipStream_t stream) {
    const float* x  = (const float*)d_in[0];
    const float* Wi = (const float*)d_in[1];
    const float* Wh = (const float*)d_in[2];
    const float* bi = (const float*)d_in[3];
    const float* bh = (const float*)d_in[4];
    float* out = (float*)d_out;

    char* w = (char*)d_ws;
    const size_t NK = (size_t)NG * H_;
    unsigned short* Wt  = (unsigned short*)w;                  // 8 MB (4 slabs)
    unsigned short* xb  = Wt + 4 * NK;                         // 16 MB
    unsigned short* Gi  = xb + (size_t)16384 * H_;             // 64 MB (blocked layout)
    unsigned* h0h       = (unsigned*)(Gi + (size_t)16384 * NG);// (T+1)*16384 u32 = 16.85 MB
    unsigned* h1h       = h0h + (size_t)(T_ + 1) * 16384;      // 16.85 MB
    unsigned* flags     = h1h + (size_t)(T_ + 1) * 16384;      // 2*128*256B = 64 KB

    hipMemsetAsync(flags, 0, 2 * 128 * FPAD * sizeof(unsigned), stream);

    transpose_cvt<<<dim3(8, 32, 4), 256, 0, stream>>>(Wi, Wh, Wt);
    cvt_bf16<<<8192, 256, 0, stream>>>(x, xb);

    // layer-0 input gates (bulk GEMM, biases baked in, blocked output)
    gemm_bt<<<dim3(256, 32), 256, 0, stream>>>(xb, Wt + 0 * NK, bi, bh, Gi);

    // fused pipelined 2-layer recurrence (wave-autonomous sync)
    lstm_fused<<<64, 256, 0, stream>>>(Gi, Wt, h0h, h1h, bi, bh,
                                       out, out + BTH, out + BTH + 2 * (size_t)BH, flags);
}